// Round 8
// baseline (155.310 us; speedup 1.0000x reference)
//
#include <hip/hip_runtime.h>
#include <hip/hip_bf16.h>

#define B 8
#define T 2048
#define C 96
#define NH 3
#define HD 32
#define FFD 2048
#define HALF_W 32
#define BT (B*T)

typedef __hip_bfloat16 bf16;
typedef __attribute__((ext_vector_type(8))) short short8;
typedef __attribute__((ext_vector_type(4))) short short4v;
typedef __attribute__((ext_vector_type(16))) float floatx16;

__device__ __forceinline__ short f2bs(float v){
    __hip_bfloat16 h = __float2bfloat16(v);
    return *reinterpret_cast<short*>(&h);
}
__device__ __forceinline__ int imin(int a, int b){ return a < b ? a : b; }
__device__ __forceinline__ int imax(int a, int b){ return a > b ? a : b; }
__device__ __forceinline__ short8 ld_b64x2(const short* p){
    short4v a = *(const short4v*)p;
    short4v b = *(const short4v*)(p + 4);
    short8 v;
    v[0]=a[0]; v[1]=a[1]; v[2]=a[2]; v[3]=a[3];
    v[4]=b[0]; v[5]=b[1]; v[6]=b[2]; v[7]=b[3];
    return v;
}

// ---------------- K0: convert all weights to bf16 ----------------
__global__ void cvtw_kernel(const float* __restrict__ wq, const float* __restrict__ wo,
                            const float* __restrict__ w1, const float* __restrict__ w2,
                            bf16* __restrict__ dst){
    int i = blockIdx.x*256 + threadIdx.x;
    if(i < 27648)       dst[i] = __float2bfloat16(wq[i]);
    else if(i < 36864)  dst[i] = __float2bfloat16(wo[i-27648]);
    else if(i < 233472) dst[i] = __float2bfloat16(w1[i-36864]);
    else if(i < 430080) dst[i] = __float2bfloat16(w2[i-233472]);
}

// ---------------- K1: QKV projection, MFMA; Q/K/V stored [type][b][h][t][32] ----------------
__global__ __launch_bounds__(256) void qkv_kernel(
    const float* __restrict__ x, const bf16* __restrict__ wq,
    const float* __restrict__ bias, bf16* __restrict__ qkvs){
    __shared__ float xs[96*36];   // [c][t], stride 36 (conflict-free for frag build)
    int b  = blockIdx.x >> 6;            // T/32 = 64 tiles per batch
    int t0 = (blockIdx.x & 63) * 32;
    for(int e = threadIdx.x; e < 96*8; e += 256){
        int c = e >> 3, t4 = e & 7;
        *(float4*)(xs + c*36 + t4*4) =
            *(const float4*)(x + (size_t)b*C*T + (size_t)c*T + t0 + t4*4);
    }
    __syncthreads();
    int r0 = b*T + t0;
    const int w = threadIdx.x >> 6, lane = threadIdx.x & 63;
    const int lm = lane & 31, hq = lane >> 5;
    short8 bfr[6];
    #pragma unroll
    for(int ks = 0; ks < 6; ++ks){
        short8 v;
        #pragma unroll
        for(int i = 0; i < 8; ++i)
            v[i] = f2bs(xs[(ks*16 + hq*8 + i)*36 + lm]);
        bfr[ks] = v;
    }
    int nacc = (w == 0) ? 3 : 2;
    int ots[3] = {w, w+4, 8};
    floatx16 acc[3];
    #pragma unroll
    for(int i = 0; i < 3; ++i)
        #pragma unroll
        for(int r = 0; r < 16; ++r) acc[i][r] = 0.f;
    #pragma unroll
    for(int i = 0; i < 3; ++i){
        if(i < nacc){
            #pragma unroll
            for(int ks = 0; ks < 6; ++ks){
                short8 af = *(const short8*)((const short*)wq
                              + (size_t)(ots[i]*32 + lm)*96 + ks*16 + hq*8);
                acc[i] = __builtin_amdgcn_mfma_f32_32x32x16_bf16(af, bfr[ks], acc[i], 0,0,0);
            }
        }
    }
    // D: col=lm=token, reg->o_local. Store [type][b][h][t][32] (line-covered rows)
    #pragma unroll
    for(int i = 0; i < 3; ++i){
        if(i < nacc){
            int type = ots[i]/3, hh = ots[i]%3;
            size_t rowbase = (((size_t)type*B*NH) + (size_t)b*NH + hh)*T + t0 + lm;
            #pragma unroll
            for(int q = 0; q < 4; ++q){
                float4 bv = *(const float4*)(bias + ots[i]*32 + 8*q + 4*hq);
                short4v pk;
                pk[0] = f2bs(acc[i][4*q+0] + bv.x);
                pk[1] = f2bs(acc[i][4*q+1] + bv.y);
                pk[2] = f2bs(acc[i][4*q+2] + bv.z);
                pk[3] = f2bs(acc[i][4*q+3] + bv.w);
                *(short4v*)((short*)qkvs + rowbase*32 + 8*q + 4*hq) = pk;
            }
        }
    }
}

// ---------------- K2: banded attention via MFMA, 64-query blocks ----------------
__global__ __launch_bounds__(128) void attn_kernel(const bf16* __restrict__ qkvs,
                                                   bf16* __restrict__ ctxh){
    __shared__ __align__(16) short VtS[32*132];     // V^T [d][key 0..127]
    __shared__ __align__(16) short PtS[2][32*100];  // per wave: P [query][key 0..95]
    __shared__ float LsS[2][32];
    int blk = blockIdx.x;
    int ntile = T/64;  // 32
    int b   = blk / (NH*ntile);
    int rem = blk % (NH*ntile);
    int h   = rem / ntile;
    int t0  = (rem % ntile) * 64;
    const short* qb = (const short*)qkvs + ((size_t)0*B*NH + (size_t)b*NH + h)*T*32;
    const short* kb = (const short*)qkvs + ((size_t)1*B*NH + (size_t)b*NH + h)*T*32;
    const short* vb = (const short*)qkvs + ((size_t)2*B*NH + (size_t)b*NH + h)*T*32;
    const int tid = threadIdx.x;
    const int w = tid >> 6, lane = tid & 63;
    const int lm = lane & 31, hq = lane >> 5;

    for(int e = tid; e < 256; e += 128){
        int kp = e >> 2, d8 = e & 3;
        int sa = imin(imax(t0 - 32 + 2*kp, 0), T-1);
        int sb = imin(imax(t0 - 32 + 2*kp + 1, 0), T-1);
        short8 va = *(const short8*)(vb + (size_t)sa*32 + d8*8);
        short8 v2 = *(const short8*)(vb + (size_t)sb*32 + d8*8);
        #pragma unroll
        for(int j = 0; j < 8; ++j){
            int val = (int)(unsigned short)va[j] | ((int)(unsigned short)v2[j] << 16);
            *(int*)(VtS + (d8*8 + j)*132 + 2*kp) = val;
        }
    }
    short8 qf0, qf1;
    {
        const short* qrow = qb + (size_t)(t0 + 32*w + lm)*32;
        qf0 = *(const short8*)(qrow + hq*8);
        qf1 = *(const short8*)(qrow + 16 + hq*8);
    }
    floatx16 S[3];
    #pragma unroll
    for(int sub = 0; sub < 3; ++sub){
        int srow = imin(imax(t0 + 32*w - 32 + sub*32 + lm, 0), T-1);
        const short* krow = kb + (size_t)srow*32;
        short8 kf0 = *(const short8*)(krow + hq*8);
        short8 kf1 = *(const short8*)(krow + 16 + hq*8);
        floatx16 z;
        #pragma unroll
        for(int r = 0; r < 16; ++r) z[r] = 0.f;
        z = __builtin_amdgcn_mfma_f32_32x32x16_bf16(kf0, qf0, z, 0,0,0);
        z = __builtin_amdgcn_mfma_f32_32x32x16_bf16(kf1, qf1, z, 0,0,0);
        S[sub] = z;
    }
    const float scale = 0.17677669529663687f;
    float part = 0.f;
    #pragma unroll
    for(int sub = 0; sub < 3; ++sub){
        #pragma unroll
        for(int r = 0; r < 16; ++r){
            int key_local = sub*32 + (r&3) + 8*(r>>2) + 4*hq;
            int s_glob = t0 + 32*w - 32 + key_local;
            int rel = key_local - lm;
            bool ok = (rel >= 0) && (rel <= 64) && (s_glob >= 0) && (s_glob < T);
            float p = ok ? __expf(S[sub][r]*scale) : 0.f;
            S[sub][r] = p;
            part += p;
        }
    }
    float ltot = part + __shfl_xor(part, 32);
    if(hq == 0) LsS[w][lm] = ltot;
    #pragma unroll
    for(int sub = 0; sub < 3; ++sub){
        #pragma unroll
        for(int q4 = 0; q4 < 4; ++q4){
            int kbase = sub*32 + 8*q4 + 4*hq;
            short4v pk;
            pk[0] = f2bs(S[sub][4*q4+0]);
            pk[1] = f2bs(S[sub][4*q4+1]);
            pk[2] = f2bs(S[sub][4*q4+2]);
            pk[3] = f2bs(S[sub][4*q4+3]);
            *(short4v*)(PtS[w] + lm*100 + kbase) = pk;
        }
    }
    __syncthreads();
    floatx16 O;
    #pragma unroll
    for(int r = 0; r < 16; ++r) O[r] = 0.f;
    #pragma unroll
    for(int ks = 0; ks < 6; ++ks){
        short8 pa = ld_b64x2(PtS[w] + lm*100 + ks*16 + hq*8);
        short8 vf = ld_b64x2(VtS + lm*132 + 32*w + ks*16 + hq*8);
        O = __builtin_amdgcn_mfma_f32_32x32x16_bf16(pa, vf, O, 0,0,0);
    }
    #pragma unroll
    for(int r = 0; r < 16; ++r){
        int qr = (r&3) + 8*(r>>2) + 4*hq;
        float linv = 1.f / LsS[w][qr];
        ((short*)ctxh)[(((size_t)b*NH + h)*T + t0 + 32*w + qr)*32 + lm] = f2bs(O[r]*linv);
    }
}

// ---------------- K3: outproj + residual(x direct) + LN1 fused ----------------
__global__ __launch_bounds__(192) void outproj_ln_kernel(
    const bf16* __restrict__ ctxh, const bf16* __restrict__ wo,
    const float* __restrict__ bias, const float* __restrict__ x,
    const float* __restrict__ g1, const float* __restrict__ bb1,
    float* __restrict__ h1, bf16* __restrict__ h1b){
    __shared__ float red[2][3][32];
    const int ct = threadIdx.x >> 6, lane = threadIdx.x & 63;
    const int lm = lane & 31, hq = lane >> 5;
    const int r0 = blockIdx.x * 32;
    const int b = r0 / T, tloc = r0 % T;
    short8 bfr[6];
    #pragma unroll
    for(int ks = 0; ks < 6; ++ks){
        int off = ks*16 + hq*8;
        int hh = off >> 5, dd = off & 31;
        bfr[ks] = *(const short8*)((const short*)ctxh
                    + (((size_t)b*NH + hh)*T + tloc + lm)*32 + dd);
    }
    floatx16 acc;
    #pragma unroll
    for(int r = 0; r < 16; ++r) acc[r] = 0.f;
    #pragma unroll
    for(int ks = 0; ks < 6; ++ks){
        short8 af = *(const short8*)((const short*)wo
                      + (size_t)(ct*32 + lm)*96 + ks*16 + hq*8);
        acc = __builtin_amdgcn_mfma_f32_32x32x16_bf16(af, bfr[ks], acc, 0,0,0);
    }
    float vals[16];
    float p1 = 0.f, p2 = 0.f;
    #pragma unroll
    for(int q = 0; q < 4; ++q){
        int c = ct*32 + 8*q + 4*hq;
        float4 bv = *(const float4*)(bias + c);
        float bva[4] = {bv.x, bv.y, bv.z, bv.w};
        #pragma unroll
        for(int r = 0; r < 4; ++r){
            float xv = x[(size_t)b*C*T + (size_t)(c + r)*T + tloc + lm];
            float v = acc[4*q+r] + bva[r] + xv;
            vals[4*q+r] = v;
            p1 += v; p2 += v*v;
        }
    }
    p1 += __shfl_xor(p1, 32);
    p2 += __shfl_xor(p2, 32);
    if(hq == 0){ red[0][ct][lm] = p1; red[1][ct][lm] = p2; }
    __syncthreads();
    float s  = red[0][0][lm] + red[0][1][lm] + red[0][2][lm];
    float s2 = red[1][0][lm] + red[1][1][lm] + red[1][2][lm];
    float mu = s * (1.0f/96.0f);
    float rstd = rsqrtf(s2*(1.0f/96.0f) - mu*mu + 1e-5f);
    int row = r0 + lm;
    #pragma unroll
    for(int q = 0; q < 4; ++q){
        int c = ct*32 + 8*q + 4*hq;
        float4 gv = *(const float4*)(g1 + c);
        float4 bv = *(const float4*)(bb1 + c);
        float ga[4] = {gv.x, gv.y, gv.z, gv.w};
        float ba[4] = {bv.x, bv.y, bv.z, bv.w};
        float4 yo;
        float ya[4];
        #pragma unroll
        for(int r = 0; r < 4; ++r)
            ya[r] = (vals[4*q+r] - mu)*rstd*ga[r] + ba[r];
        yo.x = ya[0]; yo.y = ya[1]; yo.z = ya[2]; yo.w = ya[3];
        *(float4*)(h1 + (size_t)row*96 + c) = yo;
        short4v pk;
        #pragma unroll
        for(int r = 0; r < 4; ++r) pk[r] = f2bs(ya[r]);
        *(short4v*)((short*)h1b + (size_t)row*96 + c) = pk;
    }
}

// ---------------- K4: fused FF, shfl-exchange + register-prefetch pipeline ----------------
// grid BT/32 = 512, block 256. Wave w owns j-cols [32w,32w+32) of each 128-j tile.
// FF1 D (col=m=lm, reg->j) is converted to FF2's B-frag (row=m=lm, k=j) by a
// cross-hq half-exchange per 8-j block: 8 shfl_xor(32) per iteration. No LDS, no
// barriers in the loop. w1 frags prefetched one jt ahead; w2 frags issued at
// iteration top, consumed after FF1+pack (~150+ cyc later). FF1 split into
// even/odd accumulator chains, summed inside the bias-add.
__global__ __launch_bounds__(256, 2) void ff_ln_kernel(
    const bf16* __restrict__ h1b, const float* __restrict__ h1,
    const bf16* __restrict__ w1b, const float* __restrict__ b1,
    const bf16* __restrict__ w2b, const float* __restrict__ b2,
    const float* __restrict__ g2, const float* __restrict__ bt2,
    const float* __restrict__ gf, const float* __restrict__ btf,
    float* __restrict__ out){
    __shared__ float redp[9*1088];                // waves 1..3 partials, stride-17 padded
    __shared__ float zt[96*33];                   // LN output transposed
    const int tid = threadIdx.x;
    const int w = tid >> 6, lane = tid & 63;
    const int lm = lane & 31, hq = lane >> 5;
    const int r0 = blockIdx.x * 32;
    short8 hf[6];
    #pragma unroll
    for(int ks = 0; ks < 6; ++ks)
        hf[ks] = *(const short8*)((const short*)h1b
                   + (size_t)(r0 + lm)*96 + ks*16 + hq*8);
    floatx16 acc2[3];
    #pragma unroll
    for(int i = 0; i < 3; ++i)
        #pragma unroll
        for(int r = 0; r < 16; ++r) acc2[i][r] = 0.f;

    const short* w1p = (const short*)w1b + (size_t)(w*32 + lm)*96 + hq*8;
    const short* w2p = (const short*)w2b + hq*8;
    // prologue: w1 frags for jt=0
    short8 cw1[6];
    #pragma unroll
    for(int ks = 0; ks < 6; ++ks)
        cw1[ks] = *(const short8*)(w1p + ks*16);

    #pragma unroll
    for(int jt = 0; jt < 16; ++jt){
        const int jn = (jt + 1) & 15;   // wraps on last iter (loaded, unused)
        // prefetch next jt's w1 frags + this jt's w2 frags
        short8 nw1[6], w2f[6];
        #pragma unroll
        for(int ks = 0; ks < 6; ++ks)
            nw1[ks] = *(const short8*)(w1p + (size_t)jn*128*96 + ks*16);
        #pragma unroll
        for(int g = 0; g < 2; ++g)
            #pragma unroll
            for(int ct = 0; ct < 3; ++ct)
                w2f[g*3 + ct] = *(const short8*)(w2p
                                  + (size_t)(ct*32 + lm)*FFD + jt*128 + w*32 + g*16);
        // ---- FF1 (even/odd accumulator chains)
        floatx16 aA, aB;
        #pragma unroll
        for(int r = 0; r < 16; ++r){ aA[r] = 0.f; aB[r] = 0.f; }
        #pragma unroll
        for(int ks = 0; ks < 3; ++ks){
            aA = __builtin_amdgcn_mfma_f32_32x32x16_bf16(cw1[2*ks],   hf[2*ks],   aA, 0,0,0);
            aB = __builtin_amdgcn_mfma_f32_32x32x16_bf16(cw1[2*ks+1], hf[2*ks+1], aB, 0,0,0);
        }
        // ---- pack: bias + relu + bf16, keep as int pairs (j-local = 8q+4hq+r)
        int pk[4][2];
        #pragma unroll
        for(int q = 0; q < 4; ++q){
            float4 bv = *(const float4*)(b1 + jt*128 + w*32 + 8*q + 4*hq);
            float bva[4] = {bv.x, bv.y, bv.z, bv.w};
            short4v t;
            #pragma unroll
            for(int r = 0; r < 4; ++r){
                float v = aA[4*q+r] + aB[4*q+r] + bva[r];
                t[r] = f2bs(v > 0.f ? v : 0.f);
            }
            int2 u = *(int2*)&t;
            pk[q][0] = u.x; pk[q][1] = u.y;
        }
        // ---- FF2: build B-frag via cross-hq exchange, accumulate
        #pragma unroll
        for(int g = 0; g < 2; ++g){
            int a0 = pk[2*g][0],   a1 = pk[2*g][1];
            int b0 = pk[2*g+1][0], b1v = pk[2*g+1][1];
            int ra0 = __shfl_xor(a0, 32),  ra1 = __shfl_xor(a1, 32);
            int rb0 = __shfl_xor(b0, 32),  rb1 = __shfl_xor(b1v, 32);
            int4 sfi;
            sfi.x = hq ? rb0 : a0;
            sfi.y = hq ? rb1 : a1;
            sfi.z = hq ? b0  : ra0;
            sfi.w = hq ? b1v : ra1;
            short8 sf = *(short8*)&sfi;
            #pragma unroll
            for(int ct = 0; ct < 3; ++ct)
                acc2[ct] = __builtin_amdgcn_mfma_f32_32x32x16_bf16(w2f[g*3+ct], sf, acc2[ct], 0,0,0);
        }
        #pragma unroll
        for(int ks = 0; ks < 6; ++ks) cw1[ks] = nw1[ks];
    }
    // ---- epilogue: cross-wave reduce + b2 + residual + LN2 + LNf + transpose out
    __syncthreads();
    if(w > 0){
        #pragma unroll
        for(int ct = 0; ct < 3; ++ct)
            #pragma unroll
            for(int q = 0; q < 4; ++q)
                #pragma unroll
                for(int r = 0; r < 4; ++r)
                    redp[((w-1)*3 + ct)*1088 + lane*17 + 4*q + r] = acc2[ct][4*q+r];
    }
    __syncthreads();
    if(w == 0){
        float vals[48];
        float p1 = 0.f, p2 = 0.f;
        #pragma unroll
        for(int ct = 0; ct < 3; ++ct){
            #pragma unroll
            for(int q = 0; q < 4; ++q){
                int c = ct*32 + 8*q + 4*hq;
                float4 bv = *(const float4*)(b2 + c);
                float4 rs = *(const float4*)(h1 + (size_t)(r0 + lm)*96 + c);
                float bva[4] = {bv.x, bv.y, bv.z, bv.w};
                float rsa[4] = {rs.x, rs.y, rs.z, rs.w};
                #pragma unroll
                for(int r = 0; r < 4; ++r){
                    float v = acc2[ct][4*q+r]
                            + redp[(0*3 + ct)*1088 + lane*17 + 4*q + r]
                            + redp[(1*3 + ct)*1088 + lane*17 + 4*q + r]
                            + redp[(2*3 + ct)*1088 + lane*17 + 4*q + r]
                            + bva[r] + rsa[r];
                    vals[ct*16 + 4*q + r] = v;
                    p1 += v; p2 += v*v;
                }
            }
        }
        p1 += __shfl_xor(p1, 32);
        p2 += __shfl_xor(p2, 32);
        float mu = p1*(1.0f/96.0f);
        float rstd = rsqrtf(p2*(1.0f/96.0f) - mu*mu + 1e-5f);
        float q1 = 0.f, q2 = 0.f;
        #pragma unroll
        for(int ct = 0; ct < 3; ++ct){
            #pragma unroll
            for(int q = 0; q < 4; ++q){
                int c = ct*32 + 8*q + 4*hq;
                float4 gv = *(const float4*)(g2 + c);
                float4 bv = *(const float4*)(bt2 + c);
                float ga[4] = {gv.x, gv.y, gv.z, gv.w};
                float ba[4] = {bv.x, bv.y, bv.z, bv.w};
                #pragma unroll
                for(int r = 0; r < 4; ++r){
                    float y = (vals[ct*16+4*q+r] - mu)*rstd*ga[r] + ba[r];
                    vals[ct*16+4*q+r] = y;
                    q1 += y; q2 += y*y;
                }
            }
        }
        q1 += __shfl_xor(q1, 32);
        q2 += __shfl_xor(q2, 32);
        float mu2 = q1*(1.0f/96.0f);
        float rstd2 = rsqrtf(q2*(1.0f/96.0f) - mu2*mu2 + 1e-5f);
        #pragma unroll
        for(int ct = 0; ct < 3; ++ct){
            #pragma unroll
            for(int q = 0; q < 4; ++q){
                int c = ct*32 + 8*q + 4*hq;
                float4 gv = *(const float4*)(gf + c);
                float4 bv = *(const float4*)(btf + c);
                float ga[4] = {gv.x, gv.y, gv.z, gv.w};
                float ba[4] = {bv.x, bv.y, bv.z, bv.w};
                #pragma unroll
                for(int r = 0; r < 4; ++r)
                    zt[(c + r)*33 + lm] = (vals[ct*16+4*q+r] - mu2)*rstd2*ga[r] + ba[r];
            }
        }
    }
    __syncthreads();
    int bb  = r0 / T;
    int t0g = r0 % T;
    for(int e = tid; e < 96*32; e += 256){
        int c = e >> 5, tt = e & 31;
        out[(size_t)bb*C*T + (size_t)c*T + t0g + tt] = zt[c*33 + tt];
    }
}

extern "C" void kernel_launch(void* const* d_in, const int* in_sizes, int n_in,
                              void* d_out, int out_size, void* d_ws, size_t ws_size,
                              hipStream_t stream) {
    const float* x     = (const float*)d_in[0];
    const float* w_qkv = (const float*)d_in[1];
    const float* b_qkv = (const float*)d_in[2];
    const float* w_out = (const float*)d_in[3];
    const float* b_out = (const float*)d_in[4];
    const float* ln1_g = (const float*)d_in[5];
    const float* ln1_b = (const float*)d_in[6];
    const float* w_ff1 = (const float*)d_in[7];
    const float* b_ff1 = (const float*)d_in[8];
    const float* w_ff2 = (const float*)d_in[9];
    const float* b_ff2 = (const float*)d_in[10];
    const float* ln2_g = (const float*)d_in[11];
    const float* ln2_b = (const float*)d_in[12];
    const float* lnf_g = (const float*)d_in[13];
    const float* lnf_b = (const float*)d_in[14];
    float* out = (float*)d_out;

    // ws map (bytes), total 22.9 MB:
    //   qkvs [0, 9.44M)         Q/K/V [type][b][h][t][32] bf16
    //   ctxh [9.44M, 12.58M)    ctx [b][h][t][32] bf16
    //   h1   [12.58M, 18.87M)   fp32 LN1 output
    //   h1b  [18.87M, 22.02M)   bf16 LN1 output
    //   wts  [22.02M, 22.88M)   bf16 weights
    char* wsb = (char*)d_ws;
    bf16*  qkvs  = (bf16*)wsb;
    bf16*  ctxh  = (bf16*)(wsb + 9437184);
    float* h1    = (float*)(wsb + 12582912);
    bf16*  h1b   = (bf16*)(wsb + 18874368);
    bf16*  wts   = (bf16*)(wsb + 22020096);
    bf16*  wqkvb = wts;
    bf16*  woutb = wts + 27648;
    bf16*  w1b   = wts + 36864;
    bf16*  w2b   = wts + 233472;

    cvtw_kernel      <<<1680, 256, 0, stream>>>(w_qkv, w_out, w_ff1, w_ff2, wts);
    qkv_kernel       <<<BT/32, 256, 0, stream>>>(x, wqkvb, b_qkv, qkvs);
    attn_kernel      <<<B*NH*(T/64), 128, 0, stream>>>(qkvs, ctxh);
    outproj_ln_kernel<<<BT/32, 192, 0, stream>>>(ctxh, woutb, b_out, x,
                                                 ln1_g, ln1_b, h1, h1b);
    ff_ln_kernel     <<<BT/32, 256, 0, stream>>>(h1b, h1, w1b, b_ff1, w2b, b_ff2,
                                                 ln2_g, ln2_b, lnf_g, lnf_b, out);
}

// Round 9
// 132.411 us; speedup vs baseline: 1.1729x; 1.1729x over previous
//
#include <hip/hip_runtime.h>
#include <hip/hip_bf16.h>

#define B 8
#define T 2048
#define C 96
#define NH 3
#define HD 32
#define FFD 2048
#define HALF_W 32
#define BT (B*T)

typedef __hip_bfloat16 bf16;
typedef __attribute__((ext_vector_type(8))) short short8;
typedef __attribute__((ext_vector_type(4))) short short4v;
typedef __attribute__((ext_vector_type(16))) float floatx16;

__device__ __forceinline__ short f2bs(float v){
    __hip_bfloat16 h = __float2bfloat16(v);
    return *reinterpret_cast<short*>(&h);
}
__device__ __forceinline__ int imin(int a, int b){ return a < b ? a : b; }
__device__ __forceinline__ int imax(int a, int b){ return a > b ? a : b; }
__device__ __forceinline__ short8 ld_b64x2(const short* p){
    short4v a = *(const short4v*)p;
    short4v b = *(const short4v*)(p + 4);
    short8 v;
    v[0]=a[0]; v[1]=a[1]; v[2]=a[2]; v[3]=a[3];
    v[4]=b[0]; v[5]=b[1]; v[6]=b[2]; v[7]=b[3];
    return v;
}

// ---------------- K0: convert weights to bf16 in FRAGMENT-MAJOR (swizzled) layout ----
// A-fragment for (tile,ks) at lane l=(hq<<5)|lm is 8 bf16 of row (tile*32+lm),
// k = ks*16+hq*8. Stored contiguously: fragment load = base + lane*16B (coalesced 1KB).
//   wq : [ot 0..8][ks 0..5][lane][8]                      27648
//   wo : [ct 0..2][ks 0..5][lane][8]                       9216
//   w1 : [jt 0..15][w 0..3][ks 0..5][lane][8]            196608
//   w2 : [jt 0..15][w 0..3][g 0..1][ct 0..2][lane][8]    196608
__global__ void cvtw_kernel(const float* __restrict__ wq, const float* __restrict__ wo,
                            const float* __restrict__ w1, const float* __restrict__ w2,
                            bf16* __restrict__ dst){
    int i = blockIdx.x*256 + threadIdx.x;
    if(i < 27648){
        int e = i&7, lane = (i>>3)&63, r = i>>9;
        int ks = r%6, ot = r/6;
        int o = ot*32 + (lane&31);
        int k = ks*16 + (lane>>5)*8 + e;
        dst[i] = __float2bfloat16(wq[o*96 + k]);
    } else if(i < 36864){
        int j = i - 27648;
        int e = j&7, lane = (j>>3)&63, r = j>>9;
        int ks = r%6, ct = r/6;
        int c = ct*32 + (lane&31);
        int k = ks*16 + (lane>>5)*8 + e;
        dst[i] = __float2bfloat16(wo[c*96 + k]);
    } else if(i < 233472){
        int j = i - 36864;
        int e = j&7, lane = (j>>3)&63, r = j>>9;
        int ks = r%6; r /= 6;
        int w = r%4, jt = r/4;
        int row = jt*128 + w*32 + (lane&31);
        int k = ks*16 + (lane>>5)*8 + e;
        dst[i] = __float2bfloat16(w1[row*96 + k]);
    } else if(i < 430080){
        int j = i - 233472;
        int e = j&7, lane = (j>>3)&63, r = j>>9;
        int ct = r%3; r /= 3;
        int g = r%2; r /= 2;
        int w = r%4, jt = r/4;
        int c = ct*32 + (lane&31);
        int k = jt*128 + w*32 + g*16 + (lane>>5)*8 + e;
        dst[i] = __float2bfloat16(w2[c*FFD + k]);
    }
}

// ---------------- K1: QKV projection, MFMA; Q/K/V stored [type][b][h][t][32] ----------------
__global__ __launch_bounds__(256) void qkv_kernel(
    const float* __restrict__ x, const bf16* __restrict__ wqs,
    const float* __restrict__ bias, bf16* __restrict__ qkvs){
    __shared__ float xs[96*36];   // [c][t], stride 36 (conflict-free for frag build)
    int b  = blockIdx.x >> 6;            // T/32 = 64 tiles per batch
    int t0 = (blockIdx.x & 63) * 32;
    for(int e = threadIdx.x; e < 96*8; e += 256){
        int c = e >> 3, t4 = e & 7;
        *(float4*)(xs + c*36 + t4*4) =
            *(const float4*)(x + (size_t)b*C*T + (size_t)c*T + t0 + t4*4);
    }
    __syncthreads();
    int r0 = b*T + t0;
    const int w = threadIdx.x >> 6, lane = threadIdx.x & 63;
    const int lm = lane & 31, hq = lane >> 5;
    short8 bfr[6];
    #pragma unroll
    for(int ks = 0; ks < 6; ++ks){
        short8 v;
        #pragma unroll
        for(int i = 0; i < 8; ++i)
            v[i] = f2bs(xs[(ks*16 + hq*8 + i)*36 + lm]);
        bfr[ks] = v;
    }
    int nacc = (w == 0) ? 3 : 2;
    int ots[3] = {w, w+4, 8};
    floatx16 acc[3];
    #pragma unroll
    for(int i = 0; i < 3; ++i)
        #pragma unroll
        for(int r = 0; r < 16; ++r) acc[i][r] = 0.f;
    #pragma unroll
    for(int i = 0; i < 3; ++i){
        if(i < nacc){
            #pragma unroll
            for(int ks = 0; ks < 6; ++ks){
                short8 af = *(const short8*)((const short*)wqs
                              + (size_t)(ots[i]*6 + ks)*512 + lane*8);
                acc[i] = __builtin_amdgcn_mfma_f32_32x32x16_bf16(af, bfr[ks], acc[i], 0,0,0);
            }
        }
    }
    // D: col=lm=token, reg->o_local. Store [type][b][h][t][32] (line-covered rows)
    #pragma unroll
    for(int i = 0; i < 3; ++i){
        if(i < nacc){
            int type = ots[i]/3, hh = ots[i]%3;
            size_t rowbase = (((size_t)type*B*NH) + (size_t)b*NH + hh)*T + t0 + lm;
            #pragma unroll
            for(int q = 0; q < 4; ++q){
                float4 bv = *(const float4*)(bias + ots[i]*32 + 8*q + 4*hq);
                short4v pk;
                pk[0] = f2bs(acc[i][4*q+0] + bv.x);
                pk[1] = f2bs(acc[i][4*q+1] + bv.y);
                pk[2] = f2bs(acc[i][4*q+2] + bv.z);
                pk[3] = f2bs(acc[i][4*q+3] + bv.w);
                *(short4v*)((short*)qkvs + rowbase*32 + 8*q + 4*hq) = pk;
            }
        }
    }
}

// ---------------- K2: banded attention via MFMA, 64-query blocks ----------------
__global__ __launch_bounds__(128) void attn_kernel(const bf16* __restrict__ qkvs,
                                                   bf16* __restrict__ ctxh){
    __shared__ __align__(16) short VtS[32*132];     // V^T [d][key 0..127]
    __shared__ __align__(16) short PtS[2][32*100];  // per wave: P [query][key 0..95]
    __shared__ float LsS[2][32];
    int blk = blockIdx.x;
    int ntile = T/64;  // 32
    int b   = blk / (NH*ntile);
    int rem = blk % (NH*ntile);
    int h   = rem / ntile;
    int t0  = (rem % ntile) * 64;
    const short* qb = (const short*)qkvs + ((size_t)0*B*NH + (size_t)b*NH + h)*T*32;
    const short* kb = (const short*)qkvs + ((size_t)1*B*NH + (size_t)b*NH + h)*T*32;
    const short* vb = (const short*)qkvs + ((size_t)2*B*NH + (size_t)b*NH + h)*T*32;
    const int tid = threadIdx.x;
    const int w = tid >> 6, lane = tid & 63;
    const int lm = lane & 31, hq = lane >> 5;

    for(int e = tid; e < 256; e += 128){
        int kp = e >> 2, d8 = e & 3;
        int sa = imin(imax(t0 - 32 + 2*kp, 0), T-1);
        int sb = imin(imax(t0 - 32 + 2*kp + 1, 0), T-1);
        short8 va = *(const short8*)(vb + (size_t)sa*32 + d8*8);
        short8 v2 = *(const short8*)(vb + (size_t)sb*32 + d8*8);
        #pragma unroll
        for(int j = 0; j < 8; ++j){
            int val = (int)(unsigned short)va[j] | ((int)(unsigned short)v2[j] << 16);
            *(int*)(VtS + (d8*8 + j)*132 + 2*kp) = val;
        }
    }
    short8 qf0, qf1;
    {
        const short* qrow = qb + (size_t)(t0 + 32*w + lm)*32;
        qf0 = *(const short8*)(qrow + hq*8);
        qf1 = *(const short8*)(qrow + 16 + hq*8);
    }
    floatx16 S[3];
    #pragma unroll
    for(int sub = 0; sub < 3; ++sub){
        int srow = imin(imax(t0 + 32*w - 32 + sub*32 + lm, 0), T-1);
        const short* krow = kb + (size_t)srow*32;
        short8 kf0 = *(const short8*)(krow + hq*8);
        short8 kf1 = *(const short8*)(krow + 16 + hq*8);
        floatx16 z;
        #pragma unroll
        for(int r = 0; r < 16; ++r) z[r] = 0.f;
        z = __builtin_amdgcn_mfma_f32_32x32x16_bf16(kf0, qf0, z, 0,0,0);
        z = __builtin_amdgcn_mfma_f32_32x32x16_bf16(kf1, qf1, z, 0,0,0);
        S[sub] = z;
    }
    const float scale = 0.17677669529663687f;
    float part = 0.f;
    #pragma unroll
    for(int sub = 0; sub < 3; ++sub){
        #pragma unroll
        for(int r = 0; r < 16; ++r){
            int key_local = sub*32 + (r&3) + 8*(r>>2) + 4*hq;
            int s_glob = t0 + 32*w - 32 + key_local;
            int rel = key_local - lm;
            bool ok = (rel >= 0) && (rel <= 64) && (s_glob >= 0) && (s_glob < T);
            float p = ok ? __expf(S[sub][r]*scale) : 0.f;
            S[sub][r] = p;
            part += p;
        }
    }
    float ltot = part + __shfl_xor(part, 32);
    if(hq == 0) LsS[w][lm] = ltot;
    #pragma unroll
    for(int sub = 0; sub < 3; ++sub){
        #pragma unroll
        for(int q4 = 0; q4 < 4; ++q4){
            int kbase = sub*32 + 8*q4 + 4*hq;
            short4v pk;
            pk[0] = f2bs(S[sub][4*q4+0]);
            pk[1] = f2bs(S[sub][4*q4+1]);
            pk[2] = f2bs(S[sub][4*q4+2]);
            pk[3] = f2bs(S[sub][4*q4+3]);
            *(short4v*)(PtS[w] + lm*100 + kbase) = pk;
        }
    }
    __syncthreads();
    floatx16 O;
    #pragma unroll
    for(int r = 0; r < 16; ++r) O[r] = 0.f;
    #pragma unroll
    for(int ks = 0; ks < 6; ++ks){
        short8 pa = ld_b64x2(PtS[w] + lm*100 + ks*16 + hq*8);
        short8 vf = ld_b64x2(VtS + lm*132 + 32*w + ks*16 + hq*8);
        O = __builtin_amdgcn_mfma_f32_32x32x16_bf16(pa, vf, O, 0,0,0);
    }
    #pragma unroll
    for(int r = 0; r < 16; ++r){
        int qr = (r&3) + 8*(r>>2) + 4*hq;
        float linv = 1.f / LsS[w][qr];
        ((short*)ctxh)[(((size_t)b*NH + h)*T + t0 + 32*w + qr)*32 + lm] = f2bs(O[r]*linv);
    }
}

// ---------------- K3: outproj + residual(x direct) + LN1 fused ----------------
__global__ __launch_bounds__(192) void outproj_ln_kernel(
    const bf16* __restrict__ ctxh, const bf16* __restrict__ wos,
    const float* __restrict__ bias, const float* __restrict__ x,
    const float* __restrict__ g1, const float* __restrict__ bb1,
    float* __restrict__ h1, bf16* __restrict__ h1b){
    __shared__ float red[2][3][32];
    const int ct = threadIdx.x >> 6, lane = threadIdx.x & 63;
    const int lm = lane & 31, hq = lane >> 5;
    const int r0 = blockIdx.x * 32;
    const int b = r0 / T, tloc = r0 % T;
    short8 bfr[6];
    #pragma unroll
    for(int ks = 0; ks < 6; ++ks){
        int off = ks*16 + hq*8;
        int hh = off >> 5, dd = off & 31;
        bfr[ks] = *(const short8*)((const short*)ctxh
                    + (((size_t)b*NH + hh)*T + tloc + lm)*32 + dd);
    }
    floatx16 acc;
    #pragma unroll
    for(int r = 0; r < 16; ++r) acc[r] = 0.f;
    #pragma unroll
    for(int ks = 0; ks < 6; ++ks){
        short8 af = *(const short8*)((const short*)wos
                      + (size_t)(ct*6 + ks)*512 + lane*8);
        acc = __builtin_amdgcn_mfma_f32_32x32x16_bf16(af, bfr[ks], acc, 0,0,0);
    }
    float vals[16];
    float p1 = 0.f, p2 = 0.f;
    #pragma unroll
    for(int q = 0; q < 4; ++q){
        int c = ct*32 + 8*q + 4*hq;
        float4 bv = *(const float4*)(bias + c);
        float bva[4] = {bv.x, bv.y, bv.z, bv.w};
        #pragma unroll
        for(int r = 0; r < 4; ++r){
            float xv = x[(size_t)b*C*T + (size_t)(c + r)*T + tloc + lm];
            float v = acc[4*q+r] + bva[r] + xv;
            vals[4*q+r] = v;
            p1 += v; p2 += v*v;
        }
    }
    p1 += __shfl_xor(p1, 32);
    p2 += __shfl_xor(p2, 32);
    if(hq == 0){ red[0][ct][lm] = p1; red[1][ct][lm] = p2; }
    __syncthreads();
    float s  = red[0][0][lm] + red[0][1][lm] + red[0][2][lm];
    float s2 = red[1][0][lm] + red[1][1][lm] + red[1][2][lm];
    float mu = s * (1.0f/96.0f);
    float rstd = rsqrtf(s2*(1.0f/96.0f) - mu*mu + 1e-5f);
    int row = r0 + lm;
    #pragma unroll
    for(int q = 0; q < 4; ++q){
        int c = ct*32 + 8*q + 4*hq;
        float4 gv = *(const float4*)(g1 + c);
        float4 bv = *(const float4*)(bb1 + c);
        float ga[4] = {gv.x, gv.y, gv.z, gv.w};
        float ba[4] = {bv.x, bv.y, bv.z, bv.w};
        float4 yo;
        float ya[4];
        #pragma unroll
        for(int r = 0; r < 4; ++r)
            ya[r] = (vals[4*q+r] - mu)*rstd*ga[r] + ba[r];
        yo.x = ya[0]; yo.y = ya[1]; yo.z = ya[2]; yo.w = ya[3];
        *(float4*)(h1 + (size_t)row*96 + c) = yo;
        short4v pk;
        #pragma unroll
        for(int r = 0; r < 4; ++r) pk[r] = f2bs(ya[r]);
        *(short4v*)((short*)h1b + (size_t)row*96 + c) = pk;
    }
}

// ---------------- K4: fused FF, swizzled weights + shfl-exchange pipeline ----------------
// grid BT/32 = 512, block 256. Wave w owns j-cols [32w,32w+32) of each 128-j tile.
// Weight fragment loads are now COALESCED (fragment-major layout, base+lane*16B).
__global__ __launch_bounds__(256, 2) void ff_ln_kernel(
    const bf16* __restrict__ h1b, const float* __restrict__ h1,
    const bf16* __restrict__ w1s, const float* __restrict__ b1,
    const bf16* __restrict__ w2s, const float* __restrict__ b2,
    const float* __restrict__ g2, const float* __restrict__ bt2,
    const float* __restrict__ gf, const float* __restrict__ btf,
    float* __restrict__ out){
    __shared__ float redp[9*1088];                // waves 1..3 partials, stride-17 padded
    __shared__ float zt[96*33];                   // LN output transposed
    const int tid = threadIdx.x;
    const int w = tid >> 6, lane = tid & 63;
    const int lm = lane & 31, hq = lane >> 5;
    const int r0 = blockIdx.x * 32;
    short8 hf[6];
    #pragma unroll
    for(int ks = 0; ks < 6; ++ks)
        hf[ks] = *(const short8*)((const short*)h1b
                   + (size_t)(r0 + lm)*96 + ks*16 + hq*8);
    floatx16 acc2[3];
    #pragma unroll
    for(int i = 0; i < 3; ++i)
        #pragma unroll
        for(int r = 0; r < 16; ++r) acc2[i][r] = 0.f;

    // fragment-major bases (shorts): w1: ((jt*4+w)*6+ks)*512 + lane*8
    //                                w2: (((jt*4+w)*2+g)*3+ct)*512 + lane*8
    const short* w1p = (const short*)w1s + (size_t)w*6*512 + lane*8;
    const short* w2p = (const short*)w2s + (size_t)w*2*3*512 + lane*8;
    // prologue: w1 frags for jt=0
    short8 cw1[6];
    #pragma unroll
    for(int ks = 0; ks < 6; ++ks)
        cw1[ks] = *(const short8*)(w1p + ks*512);

    #pragma unroll
    for(int jt = 0; jt < 16; ++jt){
        const int jn = (jt + 1) & 15;   // wraps on last iter (loaded, unused)
        // prefetch next jt's w1 frags + this jt's w2 frags (all coalesced 1KB)
        short8 nw1[6], w2f[6];
        #pragma unroll
        for(int ks = 0; ks < 6; ++ks)
            nw1[ks] = *(const short8*)(w1p + (size_t)jn*4*6*512 + ks*512);
        #pragma unroll
        for(int g = 0; g < 2; ++g)
            #pragma unroll
            for(int ct = 0; ct < 3; ++ct)
                w2f[g*3 + ct] = *(const short8*)(w2p
                                  + ((size_t)jt*4*2*3 + g*3 + ct)*512);
        // ---- FF1 (even/odd accumulator chains)
        floatx16 aA, aB;
        #pragma unroll
        for(int r = 0; r < 16; ++r){ aA[r] = 0.f; aB[r] = 0.f; }
        #pragma unroll
        for(int ks = 0; ks < 3; ++ks){
            aA = __builtin_amdgcn_mfma_f32_32x32x16_bf16(cw1[2*ks],   hf[2*ks],   aA, 0,0,0);
            aB = __builtin_amdgcn_mfma_f32_32x32x16_bf16(cw1[2*ks+1], hf[2*ks+1], aB, 0,0,0);
        }
        // ---- pack: bias + relu + bf16, keep as int pairs (j-local = 8q+4hq+r)
        int pk[4][2];
        #pragma unroll
        for(int q = 0; q < 4; ++q){
            float4 bv = *(const float4*)(b1 + jt*128 + w*32 + 8*q + 4*hq);
            float bva[4] = {bv.x, bv.y, bv.z, bv.w};
            short4v t;
            #pragma unroll
            for(int r = 0; r < 4; ++r){
                float v = aA[4*q+r] + aB[4*q+r] + bva[r];
                t[r] = f2bs(v > 0.f ? v : 0.f);
            }
            int2 u = *(int2*)&t;
            pk[q][0] = u.x; pk[q][1] = u.y;
        }
        // ---- FF2: build B-frag via cross-hq exchange, accumulate
        #pragma unroll
        for(int g = 0; g < 2; ++g){
            int a0 = pk[2*g][0],   a1 = pk[2*g][1];
            int b0 = pk[2*g+1][0], b1v = pk[2*g+1][1];
            int ra0 = __shfl_xor(a0, 32),  ra1 = __shfl_xor(a1, 32);
            int rb0 = __shfl_xor(b0, 32),  rb1 = __shfl_xor(b1v, 32);
            int4 sfi;
            sfi.x = hq ? rb0 : a0;
            sfi.y = hq ? rb1 : a1;
            sfi.z = hq ? b0  : ra0;
            sfi.w = hq ? b1v : ra1;
            short8 sf = *(short8*)&sfi;
            #pragma unroll
            for(int ct = 0; ct < 3; ++ct)
                acc2[ct] = __builtin_amdgcn_mfma_f32_32x32x16_bf16(w2f[g*3+ct], sf, acc2[ct], 0,0,0);
        }
        #pragma unroll
        for(int ks = 0; ks < 6; ++ks) cw1[ks] = nw1[ks];
    }
    // ---- epilogue: cross-wave reduce + b2 + residual + LN2 + LNf + transpose out
    __syncthreads();
    if(w > 0){
        #pragma unroll
        for(int ct = 0; ct < 3; ++ct)
            #pragma unroll
            for(int q = 0; q < 4; ++q)
                #pragma unroll
                for(int r = 0; r < 4; ++r)
                    redp[((w-1)*3 + ct)*1088 + lane*17 + 4*q + r] = acc2[ct][4*q+r];
    }
    __syncthreads();
    if(w == 0){
        float vals[48];
        float p1 = 0.f, p2 = 0.f;
        #pragma unroll
        for(int ct = 0; ct < 3; ++ct){
            #pragma unroll
            for(int q = 0; q < 4; ++q){
                int c = ct*32 + 8*q + 4*hq;
                float4 bv = *(const float4*)(b2 + c);
                float4 rs = *(const float4*)(h1 + (size_t)(r0 + lm)*96 + c);
                float bva[4] = {bv.x, bv.y, bv.z, bv.w};
                float rsa[4] = {rs.x, rs.y, rs.z, rs.w};
                #pragma unroll
                for(int r = 0; r < 4; ++r){
                    float v = acc2[ct][4*q+r]
                            + redp[(0*3 + ct)*1088 + lane*17 + 4*q + r]
                            + redp[(1*3 + ct)*1088 + lane*17 + 4*q + r]
                            + redp[(2*3 + ct)*1088 + lane*17 + 4*q + r]
                            + bva[r] + rsa[r];
                    vals[ct*16 + 4*q + r] = v;
                    p1 += v; p2 += v*v;
                }
            }
        }
        p1 += __shfl_xor(p1, 32);
        p2 += __shfl_xor(p2, 32);
        float mu = p1*(1.0f/96.0f);
        float rstd = rsqrtf(p2*(1.0f/96.0f) - mu*mu + 1e-5f);
        float q1 = 0.f, q2 = 0.f;
        #pragma unroll
        for(int ct = 0; ct < 3; ++ct){
            #pragma unroll
            for(int q = 0; q < 4; ++q){
                int c = ct*32 + 8*q + 4*hq;
                float4 gv = *(const float4*)(g2 + c);
                float4 bv = *(const float4*)(bt2 + c);
                float ga[4] = {gv.x, gv.y, gv.z, gv.w};
                float ba[4] = {bv.x, bv.y, bv.z, bv.w};
                #pragma unroll
                for(int r = 0; r < 4; ++r){
                    float y = (vals[ct*16+4*q+r] - mu)*rstd*ga[r] + ba[r];
                    vals[ct*16+4*q+r] = y;
                    q1 += y; q2 += y*y;
                }
            }
        }
        q1 += __shfl_xor(q1, 32);
        q2 += __shfl_xor(q2, 32);
        float mu2 = q1*(1.0f/96.0f);
        float rstd2 = rsqrtf(q2*(1.0f/96.0f) - mu2*mu2 + 1e-5f);
        #pragma unroll
        for(int ct = 0; ct < 3; ++ct){
            #pragma unroll
            for(int q = 0; q < 4; ++q){
                int c = ct*32 + 8*q + 4*hq;
                float4 gv = *(const float4*)(gf + c);
                float4 bv = *(const float4*)(btf + c);
                float ga[4] = {gv.x, gv.y, gv.z, gv.w};
                float ba[4] = {bv.x, bv.y, bv.z, bv.w};
                #pragma unroll
                for(int r = 0; r < 4; ++r)
                    zt[(c + r)*33 + lm] = (vals[ct*16+4*q+r] - mu2)*rstd2*ga[r] + ba[r];
            }
        }
    }
    __syncthreads();
    int bb  = r0 / T;
    int t0g = r0 % T;
    for(int e = tid; e < 96*32; e += 256){
        int c = e >> 5, tt = e & 31;
        out[(size_t)bb*C*T + (size_t)c*T + t0g + tt] = zt[c*33 + tt];
    }
}

extern "C" void kernel_launch(void* const* d_in, const int* in_sizes, int n_in,
                              void* d_out, int out_size, void* d_ws, size_t ws_size,
                              hipStream_t stream) {
    const float* x     = (const float*)d_in[0];
    const float* w_qkv = (const float*)d_in[1];
    const float* b_qkv = (const float*)d_in[2];
    const float* w_out = (const float*)d_in[3];
    const float* b_out = (const float*)d_in[4];
    const float* ln1_g = (const float*)d_in[5];
    const float* ln1_b = (const float*)d_in[6];
    const float* w_ff1 = (const float*)d_in[7];
    const float* b_ff1 = (const float*)d_in[8];
    const float* w_ff2 = (const float*)d_in[9];
    const float* b_ff2 = (const float*)d_in[10];
    const float* ln2_g = (const float*)d_in[11];
    const float* ln2_b = (const float*)d_in[12];
    const float* lnf_g = (const float*)d_in[13];
    const float* lnf_b = (const float*)d_in[14];
    float* out = (float*)d_out;

    // ws map (bytes), total 22.9 MB:
    //   qkvs [0, 9.44M)         Q/K/V [type][b][h][t][32] bf16
    //   ctxh [9.44M, 12.58M)    ctx [b][h][t][32] bf16
    //   h1   [12.58M, 18.87M)   fp32 LN1 output
    //   h1b  [18.87M, 22.02M)   bf16 LN1 output
    //   wts  [22.02M, 22.88M)   bf16 weights (fragment-major)
    char* wsb = (char*)d_ws;
    bf16*  qkvs  = (bf16*)wsb;
    bf16*  ctxh  = (bf16*)(wsb + 9437184);
    float* h1    = (float*)(wsb + 12582912);
    bf16*  h1b   = (bf16*)(wsb + 18874368);
    bf16*  wts   = (bf16*)(wsb + 22020096);
    bf16*  wqs   = wts;
    bf16*  wos   = wts + 27648;
    bf16*  w1s   = wts + 36864;
    bf16*  w2s   = wts + 233472;

    cvtw_kernel      <<<1680, 256, 0, stream>>>(w_qkv, w_out, w_ff1, w_ff2, wts);
    qkv_kernel       <<<BT/32, 256, 0, stream>>>(x, wqs, b_qkv, qkvs);
    attn_kernel      <<<B*NH*(T/64), 128, 0, stream>>>(qkvs, ctxh);
    outproj_ln_kernel<<<BT/32, 192, 0, stream>>>(ctxh, wos, b_out, x,
                                                 ln1_g, ln1_b, h1, h1b);
    ff_ln_kernel     <<<BT/32, 256, 0, stream>>>(h1b, h1, w1s, b_ff1, w2s, b_ff2,
                                                 ln2_g, ln2_b, lnf_g, lnf_b, out);
}

// Round 10
// 128.822 us; speedup vs baseline: 1.2056x; 1.0279x over previous
//
#include <hip/hip_runtime.h>
#include <hip/hip_bf16.h>

#define B 8
#define T 2048
#define C 96
#define NH 3
#define HD 32
#define FFD 2048
#define HALF_W 32
#define BT (B*T)

typedef __hip_bfloat16 bf16;
typedef __attribute__((ext_vector_type(8))) short short8;
typedef __attribute__((ext_vector_type(4))) short short4v;
typedef __attribute__((ext_vector_type(16))) float floatx16;

__device__ __forceinline__ short f2bs(float v){
    __hip_bfloat16 h = __float2bfloat16(v);
    return *reinterpret_cast<short*>(&h);
}
__device__ __forceinline__ float bs2f(short s){
    unsigned u = ((unsigned)(unsigned short)s) << 16;
    return __uint_as_float(u);
}
__device__ __forceinline__ int imin(int a, int b){ return a < b ? a : b; }
__device__ __forceinline__ int imax(int a, int b){ return a > b ? a : b; }
__device__ __forceinline__ short8 ld_b64x2(const short* p){
    short4v a = *(const short4v*)p;
    short4v b = *(const short4v*)(p + 4);
    short8 v;
    v[0]=a[0]; v[1]=a[1]; v[2]=a[2]; v[3]=a[3];
    v[4]=b[0]; v[5]=b[1]; v[6]=b[2]; v[7]=b[3];
    return v;
}

// ---------------- K0: convert weights to bf16 in FRAGMENT-MAJOR (swizzled) layout ----
//   wq : [ot 0..8][ks 0..5][lane][8]                      27648
//   wo : [ct 0..2][ks 0..5][lane][8]                       9216
//   w1 : [jt 0..15][w 0..3][ks 0..5][lane][8]            196608
//   w2 : [jt 0..15][w 0..3][g 0..1][ct 0..2][lane][8]    196608
__global__ void cvtw_kernel(const float* __restrict__ wq, const float* __restrict__ wo,
                            const float* __restrict__ w1, const float* __restrict__ w2,
                            bf16* __restrict__ dst){
    int i = blockIdx.x*256 + threadIdx.x;
    if(i < 27648){
        int e = i&7, lane = (i>>3)&63, r = i>>9;
        int ks = r%6, ot = r/6;
        int o = ot*32 + (lane&31);
        int k = ks*16 + (lane>>5)*8 + e;
        dst[i] = __float2bfloat16(wq[o*96 + k]);
    } else if(i < 36864){
        int j = i - 27648;
        int e = j&7, lane = (j>>3)&63, r = j>>9;
        int ks = r%6, ct = r/6;
        int c = ct*32 + (lane&31);
        int k = ks*16 + (lane>>5)*8 + e;
        dst[i] = __float2bfloat16(wo[c*96 + k]);
    } else if(i < 233472){
        int j = i - 36864;
        int e = j&7, lane = (j>>3)&63, r = j>>9;
        int ks = r%6; r /= 6;
        int w = r%4, jt = r/4;
        int row = jt*128 + w*32 + (lane&31);
        int k = ks*16 + (lane>>5)*8 + e;
        dst[i] = __float2bfloat16(w1[row*96 + k]);
    } else if(i < 430080){
        int j = i - 233472;
        int e = j&7, lane = (j>>3)&63, r = j>>9;
        int ct = r%3; r /= 3;
        int g = r%2; r /= 2;
        int w = r%4, jt = r/4;
        int c = ct*32 + (lane&31);
        int k = jt*128 + w*32 + g*16 + (lane>>5)*8 + e;
        dst[i] = __float2bfloat16(w2[c*FFD + k]);
    }
}

// ---------------- K1: QKV projection, MFMA; Q/K/V stored [type][b][h][t][32] ----------------
__global__ __launch_bounds__(256) void qkv_kernel(
    const float* __restrict__ x, const bf16* __restrict__ wqs,
    const float* __restrict__ bias, bf16* __restrict__ qkvs){
    __shared__ float xs[96*36];
    int b  = blockIdx.x >> 6;
    int t0 = (blockIdx.x & 63) * 32;
    for(int e = threadIdx.x; e < 96*8; e += 256){
        int c = e >> 3, t4 = e & 7;
        *(float4*)(xs + c*36 + t4*4) =
            *(const float4*)(x + (size_t)b*C*T + (size_t)c*T + t0 + t4*4);
    }
    __syncthreads();
    int r0 = b*T + t0;
    const int w = threadIdx.x >> 6, lane = threadIdx.x & 63;
    const int lm = lane & 31, hq = lane >> 5;
    short8 bfr[6];
    #pragma unroll
    for(int ks = 0; ks < 6; ++ks){
        short8 v;
        #pragma unroll
        for(int i = 0; i < 8; ++i)
            v[i] = f2bs(xs[(ks*16 + hq*8 + i)*36 + lm]);
        bfr[ks] = v;
    }
    int nacc = (w == 0) ? 3 : 2;
    int ots[3] = {w, w+4, 8};
    floatx16 acc[3];
    #pragma unroll
    for(int i = 0; i < 3; ++i)
        #pragma unroll
        for(int r = 0; r < 16; ++r) acc[i][r] = 0.f;
    #pragma unroll
    for(int i = 0; i < 3; ++i){
        if(i < nacc){
            #pragma unroll
            for(int ks = 0; ks < 6; ++ks){
                short8 af = *(const short8*)((const short*)wqs
                              + (size_t)(ots[i]*6 + ks)*512 + lane*8);
                acc[i] = __builtin_amdgcn_mfma_f32_32x32x16_bf16(af, bfr[ks], acc[i], 0,0,0);
            }
        }
    }
    #pragma unroll
    for(int i = 0; i < 3; ++i){
        if(i < nacc){
            int type = ots[i]/3, hh = ots[i]%3;
            size_t rowbase = (((size_t)type*B*NH) + (size_t)b*NH + hh)*T + t0 + lm;
            #pragma unroll
            for(int q = 0; q < 4; ++q){
                float4 bv = *(const float4*)(bias + ots[i]*32 + 8*q + 4*hq);
                short4v pk;
                pk[0] = f2bs(acc[i][4*q+0] + bv.x);
                pk[1] = f2bs(acc[i][4*q+1] + bv.y);
                pk[2] = f2bs(acc[i][4*q+2] + bv.z);
                pk[3] = f2bs(acc[i][4*q+3] + bv.w);
                *(short4v*)((short*)qkvs + rowbase*32 + 8*q + 4*hq) = pk;
            }
        }
    }
}

// ---------------- K2: FUSED attention + outproj + residual + LN1 ----------------
// grid B*(T/64)=256, block 384 (6 waves). Phase A: wave=(h=w>>1, half=w&1) does
// banded attention for 32 queries; O -> LDS ctxS. Phase B: wave=(mh,ct) does
// outproj MFMA from ctxS + x-residual + LN1 -> h1b (bf16 only).
__global__ __launch_bounds__(384) void attn_op_kernel(
    const bf16* __restrict__ qkvs, const bf16* __restrict__ wos,
    const float* __restrict__ bias, const float* __restrict__ x,
    const float* __restrict__ g1, const float* __restrict__ bb1,
    bf16* __restrict__ h1b){
    __shared__ __align__(16) short VtS[3*32*132];   // per head: V^T [d][key 0..127]
    __shared__ __align__(16) short PtS[6][3200];    // per wave: P [query][key 0..95]
    __shared__ float LsS[6][32];
    __shared__ __align__(16) short ctxS[64*100];    // ctx [token_local][c], stride 100
    __shared__ float red1[2][6][32];
    const int tid = threadIdx.x;
    const int w = tid / 64, lane = tid & 63;
    const int lm = lane & 31, hq = lane >> 5;
    int b  = blockIdx.x >> 5;           // T/64 = 32 tiles per batch
    int t0 = (blockIdx.x & 31) * 64;
    const int h = w >> 1, half = w & 1;

    // ---- stage V^T for all 3 heads (768 chunk-tasks over 384 threads)
    for(int e = tid; e < 768; e += 384){
        int hh = e / 256, rem = e & 255;
        int kp = rem >> 2, d8 = rem & 3;
        const short* vb = (const short*)qkvs + ((size_t)2*B*NH + (size_t)b*NH + hh)*T*32;
        int sa = imin(imax(t0 - 32 + 2*kp, 0), T-1);
        int sb = imin(imax(t0 - 32 + 2*kp + 1, 0), T-1);
        short8 va = *(const short8*)(vb + (size_t)sa*32 + d8*8);
        short8 v2 = *(const short8*)(vb + (size_t)sb*32 + d8*8);
        #pragma unroll
        for(int j = 0; j < 8; ++j){
            int val = (int)(unsigned short)va[j] | ((int)(unsigned short)v2[j] << 16);
            *(int*)(VtS + hh*32*132 + (d8*8 + j)*132 + 2*kp) = val;
        }
    }
    // ---- S phase (per wave): Q B-frag, K A-frags direct from global
    const short* qb = (const short*)qkvs + ((size_t)0*B*NH + (size_t)b*NH + h)*T*32;
    const short* kb = (const short*)qkvs + ((size_t)1*B*NH + (size_t)b*NH + h)*T*32;
    short8 qf0, qf1;
    {
        const short* qrow = qb + (size_t)(t0 + 32*half + lm)*32;
        qf0 = *(const short8*)(qrow + hq*8);
        qf1 = *(const short8*)(qrow + 16 + hq*8);
    }
    floatx16 S[3];
    #pragma unroll
    for(int sub = 0; sub < 3; ++sub){
        int srow = imin(imax(t0 + 32*half - 32 + sub*32 + lm, 0), T-1);
        const short* krow = kb + (size_t)srow*32;
        short8 kf0 = *(const short8*)(krow + hq*8);
        short8 kf1 = *(const short8*)(krow + 16 + hq*8);
        floatx16 z;
        #pragma unroll
        for(int r = 0; r < 16; ++r) z[r] = 0.f;
        z = __builtin_amdgcn_mfma_f32_32x32x16_bf16(kf0, qf0, z, 0,0,0);
        z = __builtin_amdgcn_mfma_f32_32x32x16_bf16(kf1, qf1, z, 0,0,0);
        S[sub] = z;
    }
    // ---- masked exp + per-query sums
    const float scale = 0.17677669529663687f;
    float part = 0.f;
    #pragma unroll
    for(int sub = 0; sub < 3; ++sub){
        #pragma unroll
        for(int r = 0; r < 16; ++r){
            int key_local = sub*32 + (r&3) + 8*(r>>2) + 4*hq;
            int s_glob = t0 + 32*half - 32 + key_local;
            int rel = key_local - lm;
            bool ok = (rel >= 0) && (rel <= 64) && (s_glob >= 0) && (s_glob < T);
            float p = ok ? __expf(S[sub][r]*scale) : 0.f;
            S[sub][r] = p;
            part += p;
        }
    }
    float ltot = part + __shfl_xor(part, 32);
    if(hq == 0) LsS[w][lm] = ltot;
    // ---- P -> LDS transposed (wave-private region)
    #pragma unroll
    for(int sub = 0; sub < 3; ++sub){
        #pragma unroll
        for(int q4 = 0; q4 < 4; ++q4){
            int kbase = sub*32 + 8*q4 + 4*hq;
            short4v pk;
            pk[0] = f2bs(S[sub][4*q4+0]);
            pk[1] = f2bs(S[sub][4*q4+1]);
            pk[2] = f2bs(S[sub][4*q4+2]);
            pk[3] = f2bs(S[sub][4*q4+3]);
            *(short4v*)(PtS[w] + lm*100 + kbase) = pk;
        }
    }
    __syncthreads();   // VtS + PtS visible
    // ---- PV
    floatx16 O;
    #pragma unroll
    for(int r = 0; r < 16; ++r) O[r] = 0.f;
    #pragma unroll
    for(int ks = 0; ks < 6; ++ks){
        short8 pa = ld_b64x2(PtS[w] + lm*100 + ks*16 + hq*8);
        short8 vf = ld_b64x2(VtS + h*32*132 + lm*132 + 32*half + ks*16 + hq*8);
        O = __builtin_amdgcn_mfma_f32_32x32x16_bf16(pa, vf, O, 0,0,0);
    }
    // ---- O/l -> ctxS
    #pragma unroll
    for(int r = 0; r < 16; ++r){
        int qr = (r&3) + 8*(r>>2) + 4*hq;
        float linv = 1.f / LsS[w][qr];
        ctxS[(32*half + qr)*100 + h*32 + lm] = f2bs(O[r]*linv);
    }
    __syncthreads();   // ctxS ready

    // ======== Phase B: outproj + residual + LN1 ========
    const int mh = (w >= 3) ? 1 : 0;
    const int ct = w - 3*mh;
    short8 bfr[6];
    #pragma unroll
    for(int ks = 0; ks < 6; ++ks)
        bfr[ks] = ld_b64x2(ctxS + (mh*32 + lm)*100 + ks*16 + hq*8);
    floatx16 acc;
    #pragma unroll
    for(int r = 0; r < 16; ++r) acc[r] = 0.f;
    #pragma unroll
    for(int ks = 0; ks < 6; ++ks){
        short8 af = *(const short8*)((const short*)wos
                      + (size_t)(ct*6 + ks)*512 + lane*8);
        acc = __builtin_amdgcn_mfma_f32_32x32x16_bf16(af, bfr[ks], acc, 0,0,0);
    }
    const int tloc = t0 + mh*32;
    float vals[16];
    float p1 = 0.f, p2 = 0.f;
    #pragma unroll
    for(int q = 0; q < 4; ++q){
        int c = ct*32 + 8*q + 4*hq;
        float4 bv = *(const float4*)(bias + c);
        float bva[4] = {bv.x, bv.y, bv.z, bv.w};
        #pragma unroll
        for(int r = 0; r < 4; ++r){
            float xv = x[(size_t)b*C*T + (size_t)(c + r)*T + tloc + lm];
            float v = acc[4*q+r] + bva[r] + xv;
            vals[4*q+r] = v;
            p1 += v; p2 += v*v;
        }
    }
    p1 += __shfl_xor(p1, 32);
    p2 += __shfl_xor(p2, 32);
    if(hq == 0){ red1[0][w][lm] = p1; red1[1][w][lm] = p2; }
    __syncthreads();
    float s  = red1[0][mh*3+0][lm] + red1[0][mh*3+1][lm] + red1[0][mh*3+2][lm];
    float s2 = red1[1][mh*3+0][lm] + red1[1][mh*3+1][lm] + red1[1][mh*3+2][lm];
    float mu = s * (1.0f/96.0f);
    float rstd = rsqrtf(s2*(1.0f/96.0f) - mu*mu + 1e-5f);
    int row = b*T + tloc + lm;
    #pragma unroll
    for(int q = 0; q < 4; ++q){
        int c = ct*32 + 8*q + 4*hq;
        float4 gv = *(const float4*)(g1 + c);
        float4 bv = *(const float4*)(bb1 + c);
        float ga[4] = {gv.x, gv.y, gv.z, gv.w};
        float ba[4] = {bv.x, bv.y, bv.z, bv.w};
        short4v pk;
        #pragma unroll
        for(int r = 0; r < 4; ++r)
            pk[r] = f2bs((vals[4*q+r] - mu)*rstd*ga[r] + ba[r]);
        *(short4v*)((short*)h1b + (size_t)row*96 + c) = pk;
    }
}

// ---------------- K3: fused FF, swizzled weights + shfl-exchange pipeline ----------------
// Residual now taken from h1b (bf16) — no fp32 h1 buffer.
__global__ __launch_bounds__(256, 2) void ff_ln_kernel(
    const bf16* __restrict__ h1b,
    const bf16* __restrict__ w1s, const float* __restrict__ b1,
    const bf16* __restrict__ w2s, const float* __restrict__ b2,
    const float* __restrict__ g2, const float* __restrict__ bt2,
    const float* __restrict__ gf, const float* __restrict__ btf,
    float* __restrict__ out){
    __shared__ float redp[9*1088];
    __shared__ float zt[96*33];
    const int tid = threadIdx.x;
    const int w = tid >> 6, lane = tid & 63;
    const int lm = lane & 31, hq = lane >> 5;
    const int r0 = blockIdx.x * 32;
    short8 hf[6];
    #pragma unroll
    for(int ks = 0; ks < 6; ++ks)
        hf[ks] = *(const short8*)((const short*)h1b
                   + (size_t)(r0 + lm)*96 + ks*16 + hq*8);
    floatx16 acc2[3];
    #pragma unroll
    for(int i = 0; i < 3; ++i)
        #pragma unroll
        for(int r = 0; r < 16; ++r) acc2[i][r] = 0.f;

    const short* w1p = (const short*)w1s + (size_t)w*6*512 + lane*8;
    const short* w2p = (const short*)w2s + (size_t)w*2*3*512 + lane*8;
    short8 cw1[6];
    #pragma unroll
    for(int ks = 0; ks < 6; ++ks)
        cw1[ks] = *(const short8*)(w1p + ks*512);

    #pragma unroll
    for(int jt = 0; jt < 16; ++jt){
        const int jn = (jt + 1) & 15;
        short8 nw1[6], w2f[6];
        #pragma unroll
        for(int ks = 0; ks < 6; ++ks)
            nw1[ks] = *(const short8*)(w1p + (size_t)jn*4*6*512 + ks*512);
        #pragma unroll
        for(int g = 0; g < 2; ++g)
            #pragma unroll
            for(int ct = 0; ct < 3; ++ct)
                w2f[g*3 + ct] = *(const short8*)(w2p
                                  + ((size_t)jt*4*2*3 + g*3 + ct)*512);
        floatx16 aA, aB;
        #pragma unroll
        for(int r = 0; r < 16; ++r){ aA[r] = 0.f; aB[r] = 0.f; }
        #pragma unroll
        for(int ks = 0; ks < 3; ++ks){
            aA = __builtin_amdgcn_mfma_f32_32x32x16_bf16(cw1[2*ks],   hf[2*ks],   aA, 0,0,0);
            aB = __builtin_amdgcn_mfma_f32_32x32x16_bf16(cw1[2*ks+1], hf[2*ks+1], aB, 0,0,0);
        }
        int pk[4][2];
        #pragma unroll
        for(int q = 0; q < 4; ++q){
            float4 bv = *(const float4*)(b1 + jt*128 + w*32 + 8*q + 4*hq);
            float bva[4] = {bv.x, bv.y, bv.z, bv.w};
            short4v t;
            #pragma unroll
            for(int r = 0; r < 4; ++r){
                float v = aA[4*q+r] + aB[4*q+r] + bva[r];
                t[r] = f2bs(v > 0.f ? v : 0.f);
            }
            int2 u = *(int2*)&t;
            pk[q][0] = u.x; pk[q][1] = u.y;
        }
        #pragma unroll
        for(int g = 0; g < 2; ++g){
            int a0 = pk[2*g][0],   a1 = pk[2*g][1];
            int b0 = pk[2*g+1][0], b1v = pk[2*g+1][1];
            int ra0 = __shfl_xor(a0, 32),  ra1 = __shfl_xor(a1, 32);
            int rb0 = __shfl_xor(b0, 32),  rb1 = __shfl_xor(b1v, 32);
            int4 sfi;
            sfi.x = hq ? rb0 : a0;
            sfi.y = hq ? rb1 : a1;
            sfi.z = hq ? b0  : ra0;
            sfi.w = hq ? b1v : ra1;
            short8 sf = *(short8*)&sfi;
            #pragma unroll
            for(int ct = 0; ct < 3; ++ct)
                acc2[ct] = __builtin_amdgcn_mfma_f32_32x32x16_bf16(w2f[g*3+ct], sf, acc2[ct], 0,0,0);
        }
        #pragma unroll
        for(int ks = 0; ks < 6; ++ks) cw1[ks] = nw1[ks];
    }
    __syncthreads();
    if(w > 0){
        #pragma unroll
        for(int ct = 0; ct < 3; ++ct)
            #pragma unroll
            for(int q = 0; q < 4; ++q)
                #pragma unroll
                for(int r = 0; r < 4; ++r)
                    redp[((w-1)*3 + ct)*1088 + lane*17 + 4*q + r] = acc2[ct][4*q+r];
    }
    __syncthreads();
    if(w == 0){
        float vals[48];
        float p1 = 0.f, p2 = 0.f;
        #pragma unroll
        for(int ct = 0; ct < 3; ++ct){
            #pragma unroll
            for(int q = 0; q < 4; ++q){
                int c = ct*32 + 8*q + 4*hq;
                float4 bv = *(const float4*)(b2 + c);
                short4v hv = *(const short4v*)((const short*)h1b + (size_t)(r0 + lm)*96 + c);
                float bva[4] = {bv.x, bv.y, bv.z, bv.w};
                #pragma unroll
                for(int r = 0; r < 4; ++r){
                    float v = acc2[ct][4*q+r]
                            + redp[(0*3 + ct)*1088 + lane*17 + 4*q + r]
                            + redp[(1*3 + ct)*1088 + lane*17 + 4*q + r]
                            + redp[(2*3 + ct)*1088 + lane*17 + 4*q + r]
                            + bva[r] + bs2f(hv[r]);
                    vals[ct*16 + 4*q + r] = v;
                    p1 += v; p2 += v*v;
                }
            }
        }
        p1 += __shfl_xor(p1, 32);
        p2 += __shfl_xor(p2, 32);
        float mu = p1*(1.0f/96.0f);
        float rstd = rsqrtf(p2*(1.0f/96.0f) - mu*mu + 1e-5f);
        float q1 = 0.f, q2 = 0.f;
        #pragma unroll
        for(int ct = 0; ct < 3; ++ct){
            #pragma unroll
            for(int q = 0; q < 4; ++q){
                int c = ct*32 + 8*q + 4*hq;
                float4 gv = *(const float4*)(g2 + c);
                float4 bv = *(const float4*)(bt2 + c);
                float ga[4] = {gv.x, gv.y, gv.z, gv.w};
                float ba[4] = {bv.x, bv.y, bv.z, bv.w};
                #pragma unroll
                for(int r = 0; r < 4; ++r){
                    float y = (vals[ct*16+4*q+r] - mu)*rstd*ga[r] + ba[r];
                    vals[ct*16+4*q+r] = y;
                    q1 += y; q2 += y*y;
                }
            }
        }
        q1 += __shfl_xor(q1, 32);
        q2 += __shfl_xor(q2, 32);
        float mu2 = q1*(1.0f/96.0f);
        float rstd2 = rsqrtf(q2*(1.0f/96.0f) - mu2*mu2 + 1e-5f);
        #pragma unroll
        for(int ct = 0; ct < 3; ++ct){
            #pragma unroll
            for(int q = 0; q < 4; ++q){
                int c = ct*32 + 8*q + 4*hq;
                float4 gv = *(const float4*)(gf + c);
                float4 bv = *(const float4*)(btf + c);
                float ga[4] = {gv.x, gv.y, gv.z, gv.w};
                float ba[4] = {bv.x, bv.y, bv.z, bv.w};
                #pragma unroll
                for(int r = 0; r < 4; ++r)
                    zt[(c + r)*33 + lm] = (vals[ct*16+4*q+r] - mu2)*rstd2*ga[r] + ba[r];
            }
        }
    }
    __syncthreads();
    int bb  = r0 / T;
    int t0g = r0 % T;
    for(int e = tid; e < 96*32; e += 256){
        int c = e >> 5, tt = e & 31;
        out[(size_t)bb*C*T + (size_t)c*T + t0g + tt] = zt[c*33 + tt];
    }
}

extern "C" void kernel_launch(void* const* d_in, const int* in_sizes, int n_in,
                              void* d_out, int out_size, void* d_ws, size_t ws_size,
                              hipStream_t stream) {
    const float* x     = (const float*)d_in[0];
    const float* w_qkv = (const float*)d_in[1];
    const float* b_qkv = (const float*)d_in[2];
    const float* w_out = (const float*)d_in[3];
    const float* b_out = (const float*)d_in[4];
    const float* ln1_g = (const float*)d_in[5];
    const float* ln1_b = (const float*)d_in[6];
    const float* w_ff1 = (const float*)d_in[7];
    const float* b_ff1 = (const float*)d_in[8];
    const float* w_ff2 = (const float*)d_in[9];
    const float* b_ff2 = (const float*)d_in[10];
    const float* ln2_g = (const float*)d_in[11];
    const float* ln2_b = (const float*)d_in[12];
    const float* lnf_g = (const float*)d_in[13];
    const float* lnf_b = (const float*)d_in[14];
    float* out = (float*)d_out;

    // ws map (bytes), total 13.4 MB:
    //   qkvs [0, 9.44M)         Q/K/V [type][b][h][t][32] bf16
    //   h1b  [9.44M, 12.58M)    bf16 LN1 output
    //   wts  [12.58M, 13.44M)   bf16 weights (fragment-major)
    char* wsb = (char*)d_ws;
    bf16*  qkvs  = (bf16*)wsb;
    bf16*  h1b   = (bf16*)(wsb + 9437184);
    bf16*  wts   = (bf16*)(wsb + 12582912);
    bf16*  wqs   = wts;
    bf16*  wos   = wts + 27648;
    bf16*  w1s   = wts + 36864;
    bf16*  w2s   = wts + 233472;

    cvtw_kernel   <<<1680, 256, 0, stream>>>(w_qkv, w_out, w_ff1, w_ff2, wts);
    qkv_kernel    <<<BT/32, 256, 0, stream>>>(x, wqs, b_qkv, qkvs);
    attn_op_kernel<<<B*(T/64), 384, 0, stream>>>(qkvs, wos, b_out, x,
                                                 ln1_g, ln1_b, h1b);
    ff_ln_kernel  <<<BT/32, 256, 0, stream>>>(h1b, w1s, b_ff1, w2s, b_ff2,
                                              ln2_g, ln2_b, lnf_g, lnf_b, out);
}

// Round 11
// 126.606 us; speedup vs baseline: 1.2267x; 1.0175x over previous
//
#include <hip/hip_runtime.h>
#include <hip/hip_bf16.h>

#define B 8
#define T 2048
#define C 96
#define NH 3
#define HD 32
#define FFD 2048
#define HALF_W 32
#define BT (B*T)

typedef __hip_bfloat16 bf16;
typedef __attribute__((ext_vector_type(8))) short short8;
typedef __attribute__((ext_vector_type(4))) short short4v;
typedef __attribute__((ext_vector_type(16))) float floatx16;

__device__ __forceinline__ short f2bs(float v){
    __hip_bfloat16 h = __float2bfloat16(v);
    return *reinterpret_cast<short*>(&h);
}
__device__ __forceinline__ float bs2f(short s){
    unsigned u = ((unsigned)(unsigned short)s) << 16;
    return __uint_as_float(u);
}
__device__ __forceinline__ int imin(int a, int b){ return a < b ? a : b; }
__device__ __forceinline__ int imax(int a, int b){ return a > b ? a : b; }
__device__ __forceinline__ short8 ld_b64x2(const short* p){
    short4v a = *(const short4v*)p;
    short4v b = *(const short4v*)(p + 4);
    short8 v;
    v[0]=a[0]; v[1]=a[1]; v[2]=a[2]; v[3]=a[3];
    v[4]=b[0]; v[5]=b[1]; v[6]=b[2]; v[7]=b[3];
    return v;
}

// ---------------- K0: convert weights to bf16 in FRAGMENT-MAJOR (swizzled) layout ----
//   wq : [ot 0..8][ks 0..5][lane][8]                      27648
//   wo : [ct 0..2][ks 0..5][lane][8]                       9216
//   w1 : [jt 0..15][w4 0..3][ks 0..5][lane][8]           196608
//   w2 : [jt 0..15][w4 0..3][g 0..1][ct 0..2][lane][8]   196608
__global__ void cvtw_kernel(const float* __restrict__ wq, const float* __restrict__ wo,
                            const float* __restrict__ w1, const float* __restrict__ w2,
                            bf16* __restrict__ dst){
    int i = blockIdx.x*256 + threadIdx.x;
    if(i < 27648){
        int e = i&7, lane = (i>>3)&63, r = i>>9;
        int ks = r%6, ot = r/6;
        int o = ot*32 + (lane&31);
        int k = ks*16 + (lane>>5)*8 + e;
        dst[i] = __float2bfloat16(wq[o*96 + k]);
    } else if(i < 36864){
        int j = i - 27648;
        int e = j&7, lane = (j>>3)&63, r = j>>9;
        int ks = r%6, ct = r/6;
        int c = ct*32 + (lane&31);
        int k = ks*16 + (lane>>5)*8 + e;
        dst[i] = __float2bfloat16(wo[c*96 + k]);
    } else if(i < 233472){
        int j = i - 36864;
        int e = j&7, lane = (j>>3)&63, r = j>>9;
        int ks = r%6; r /= 6;
        int w = r%4, jt = r/4;
        int row = jt*128 + w*32 + (lane&31);
        int k = ks*16 + (lane>>5)*8 + e;
        dst[i] = __float2bfloat16(w1[row*96 + k]);
    } else if(i < 430080){
        int j = i - 233472;
        int e = j&7, lane = (j>>3)&63, r = j>>9;
        int ct = r%3; r /= 3;
        int g = r%2; r /= 2;
        int w = r%4, jt = r/4;
        int c = ct*32 + (lane&31);
        int k = jt*128 + w*32 + g*16 + (lane>>5)*8 + e;
        dst[i] = __float2bfloat16(w2[c*FFD + k]);
    }
}

// ---------------- K1: QKV projection, MFMA; Q/K/V stored [type][b][h][t][32] ----------------
__global__ __launch_bounds__(256) void qkv_kernel(
    const float* __restrict__ x, const bf16* __restrict__ wqs,
    const float* __restrict__ bias, bf16* __restrict__ qkvs){
    __shared__ float xs[96*36];
    int b  = blockIdx.x >> 6;
    int t0 = (blockIdx.x & 63) * 32;
    for(int e = threadIdx.x; e < 96*8; e += 256){
        int c = e >> 3, t4 = e & 7;
        *(float4*)(xs + c*36 + t4*4) =
            *(const float4*)(x + (size_t)b*C*T + (size_t)c*T + t0 + t4*4);
    }
    __syncthreads();
    int r0 = b*T + t0;
    const int w = threadIdx.x >> 6, lane = threadIdx.x & 63;
    const int lm = lane & 31, hq = lane >> 5;
    short8 bfr[6];
    #pragma unroll
    for(int ks = 0; ks < 6; ++ks){
        short8 v;
        #pragma unroll
        for(int i = 0; i < 8; ++i)
            v[i] = f2bs(xs[(ks*16 + hq*8 + i)*36 + lm]);
        bfr[ks] = v;
    }
    int nacc = (w == 0) ? 3 : 2;
    int ots[3] = {w, w+4, 8};
    floatx16 acc[3];
    #pragma unroll
    for(int i = 0; i < 3; ++i)
        #pragma unroll
        for(int r = 0; r < 16; ++r) acc[i][r] = 0.f;
    #pragma unroll
    for(int i = 0; i < 3; ++i){
        if(i < nacc){
            #pragma unroll
            for(int ks = 0; ks < 6; ++ks){
                short8 af = *(const short8*)((const short*)wqs
                              + (size_t)(ots[i]*6 + ks)*512 + lane*8);
                acc[i] = __builtin_amdgcn_mfma_f32_32x32x16_bf16(af, bfr[ks], acc[i], 0,0,0);
            }
        }
    }
    #pragma unroll
    for(int i = 0; i < 3; ++i){
        if(i < nacc){
            int type = ots[i]/3, hh = ots[i]%3;
            size_t rowbase = (((size_t)type*B*NH) + (size_t)b*NH + hh)*T + t0 + lm;
            #pragma unroll
            for(int q = 0; q < 4; ++q){
                float4 bv = *(const float4*)(bias + ots[i]*32 + 8*q + 4*hq);
                short4v pk;
                pk[0] = f2bs(acc[i][4*q+0] + bv.x);
                pk[1] = f2bs(acc[i][4*q+1] + bv.y);
                pk[2] = f2bs(acc[i][4*q+2] + bv.z);
                pk[3] = f2bs(acc[i][4*q+3] + bv.w);
                *(short4v*)((short*)qkvs + rowbase*32 + 8*q + 4*hq) = pk;
            }
        }
    }
}

// ---------------- K2: FUSED attention + outproj + residual + LN1 ----------------
// grid B*(T/64)=256, block 384 (6 waves). Phase-B wos fragments preloaded at top.
__global__ __launch_bounds__(384) void attn_op_kernel(
    const bf16* __restrict__ qkvs, const bf16* __restrict__ wos,
    const float* __restrict__ bias, const float* __restrict__ x,
    const float* __restrict__ g1, const float* __restrict__ bb1,
    bf16* __restrict__ h1b){
    __shared__ __align__(16) short VtS[3*32*132];   // per head: V^T [d][key 0..127]
    __shared__ __align__(16) short PtS[6][3200];    // per wave: P [query][key 0..95]
    __shared__ float LsS[6][32];
    __shared__ __align__(16) short ctxS[64*100];    // ctx [token_local][c], stride 100
    __shared__ float red1[2][6][32];
    const int tid = threadIdx.x;
    const int w = tid / 64, lane = tid & 63;
    const int lm = lane & 31, hq = lane >> 5;
    int b  = blockIdx.x >> 5;
    int t0 = (blockIdx.x & 31) * 64;
    const int h = w >> 1, half = w & 1;
    const int mh = (w >= 3) ? 1 : 0;
    const int ct = w - 3*mh;

    // preload phase-B weight fragments (consumed after 2 barriers — fully hidden)
    short8 wof[6];
    #pragma unroll
    for(int ks = 0; ks < 6; ++ks)
        wof[ks] = *(const short8*)((const short*)wos + (size_t)(ct*6 + ks)*512 + lane*8);

    // ---- stage V^T for all 3 heads
    for(int e = tid; e < 768; e += 384){
        int hh = e / 256, rem = e & 255;
        int kp = rem >> 2, d8 = rem & 3;
        const short* vb = (const short*)qkvs + ((size_t)2*B*NH + (size_t)b*NH + hh)*T*32;
        int sa = imin(imax(t0 - 32 + 2*kp, 0), T-1);
        int sb = imin(imax(t0 - 32 + 2*kp + 1, 0), T-1);
        short8 va = *(const short8*)(vb + (size_t)sa*32 + d8*8);
        short8 v2 = *(const short8*)(vb + (size_t)sb*32 + d8*8);
        #pragma unroll
        for(int j = 0; j < 8; ++j){
            int val = (int)(unsigned short)va[j] | ((int)(unsigned short)v2[j] << 16);
            *(int*)(VtS + hh*32*132 + (d8*8 + j)*132 + 2*kp) = val;
        }
    }
    // ---- S phase
    const short* qb = (const short*)qkvs + ((size_t)0*B*NH + (size_t)b*NH + h)*T*32;
    const short* kb = (const short*)qkvs + ((size_t)1*B*NH + (size_t)b*NH + h)*T*32;
    short8 qf0, qf1;
    {
        const short* qrow = qb + (size_t)(t0 + 32*half + lm)*32;
        qf0 = *(const short8*)(qrow + hq*8);
        qf1 = *(const short8*)(qrow + 16 + hq*8);
    }
    floatx16 S[3];
    #pragma unroll
    for(int sub = 0; sub < 3; ++sub){
        int srow = imin(imax(t0 + 32*half - 32 + sub*32 + lm, 0), T-1);
        const short* krow = kb + (size_t)srow*32;
        short8 kf0 = *(const short8*)(krow + hq*8);
        short8 kf1 = *(const short8*)(krow + 16 + hq*8);
        floatx16 z;
        #pragma unroll
        for(int r = 0; r < 16; ++r) z[r] = 0.f;
        z = __builtin_amdgcn_mfma_f32_32x32x16_bf16(kf0, qf0, z, 0,0,0);
        z = __builtin_amdgcn_mfma_f32_32x32x16_bf16(kf1, qf1, z, 0,0,0);
        S[sub] = z;
    }
    const float scale = 0.17677669529663687f;
    float part = 0.f;
    #pragma unroll
    for(int sub = 0; sub < 3; ++sub){
        #pragma unroll
        for(int r = 0; r < 16; ++r){
            int key_local = sub*32 + (r&3) + 8*(r>>2) + 4*hq;
            int s_glob = t0 + 32*half - 32 + key_local;
            int rel = key_local - lm;
            bool ok = (rel >= 0) && (rel <= 64) && (s_glob >= 0) && (s_glob < T);
            float p = ok ? __expf(S[sub][r]*scale) : 0.f;
            S[sub][r] = p;
            part += p;
        }
    }
    float ltot = part + __shfl_xor(part, 32);
    if(hq == 0) LsS[w][lm] = ltot;
    #pragma unroll
    for(int sub = 0; sub < 3; ++sub){
        #pragma unroll
        for(int q4 = 0; q4 < 4; ++q4){
            int kbase = sub*32 + 8*q4 + 4*hq;
            short4v pk;
            pk[0] = f2bs(S[sub][4*q4+0]);
            pk[1] = f2bs(S[sub][4*q4+1]);
            pk[2] = f2bs(S[sub][4*q4+2]);
            pk[3] = f2bs(S[sub][4*q4+3]);
            *(short4v*)(PtS[w] + lm*100 + kbase) = pk;
        }
    }
    __syncthreads();
    floatx16 O;
    #pragma unroll
    for(int r = 0; r < 16; ++r) O[r] = 0.f;
    #pragma unroll
    for(int ks = 0; ks < 6; ++ks){
        short8 pa = ld_b64x2(PtS[w] + lm*100 + ks*16 + hq*8);
        short8 vf = ld_b64x2(VtS + h*32*132 + lm*132 + 32*half + ks*16 + hq*8);
        O = __builtin_amdgcn_mfma_f32_32x32x16_bf16(pa, vf, O, 0,0,0);
    }
    #pragma unroll
    for(int r = 0; r < 16; ++r){
        int qr = (r&3) + 8*(r>>2) + 4*hq;
        float linv = 1.f / LsS[w][qr];
        ctxS[(32*half + qr)*100 + h*32 + lm] = f2bs(O[r]*linv);
    }
    __syncthreads();

    // ======== Phase B: outproj + residual + LN1 ========
    short8 bfr[6];
    #pragma unroll
    for(int ks = 0; ks < 6; ++ks)
        bfr[ks] = ld_b64x2(ctxS + (mh*32 + lm)*100 + ks*16 + hq*8);
    floatx16 acc;
    #pragma unroll
    for(int r = 0; r < 16; ++r) acc[r] = 0.f;
    #pragma unroll
    for(int ks = 0; ks < 6; ++ks)
        acc = __builtin_amdgcn_mfma_f32_32x32x16_bf16(wof[ks], bfr[ks], acc, 0,0,0);
    const int tloc = t0 + mh*32;
    float vals[16];
    float p1 = 0.f, p2 = 0.f;
    #pragma unroll
    for(int q = 0; q < 4; ++q){
        int c = ct*32 + 8*q + 4*hq;
        float4 bv = *(const float4*)(bias + c);
        float bva[4] = {bv.x, bv.y, bv.z, bv.w};
        #pragma unroll
        for(int r = 0; r < 4; ++r){
            float xv = x[(size_t)b*C*T + (size_t)(c + r)*T + tloc + lm];
            float v = acc[4*q+r] + bva[r] + xv;
            vals[4*q+r] = v;
            p1 += v; p2 += v*v;
        }
    }
    p1 += __shfl_xor(p1, 32);
    p2 += __shfl_xor(p2, 32);
    if(hq == 0){ red1[0][w][lm] = p1; red1[1][w][lm] = p2; }
    __syncthreads();
    float s  = red1[0][mh*3+0][lm] + red1[0][mh*3+1][lm] + red1[0][mh*3+2][lm];
    float s2 = red1[1][mh*3+0][lm] + red1[1][mh*3+1][lm] + red1[1][mh*3+2][lm];
    float mu = s * (1.0f/96.0f);
    float rstd = rsqrtf(s2*(1.0f/96.0f) - mu*mu + 1e-5f);
    int row = b*T + tloc + lm;
    #pragma unroll
    for(int q = 0; q < 4; ++q){
        int c = ct*32 + 8*q + 4*hq;
        float4 gv = *(const float4*)(g1 + c);
        float4 bv = *(const float4*)(bb1 + c);
        float ga[4] = {gv.x, gv.y, gv.z, gv.w};
        float ba[4] = {bv.x, bv.y, bv.z, bv.w};
        short4v pk;
        #pragma unroll
        for(int r = 0; r < 4; ++r)
            pk[r] = f2bs((vals[4*q+r] - mu)*rstd*ga[r] + ba[r]);
        *(short4v*)((short*)h1b + (size_t)row*96 + c) = pk;
    }
}

// ---------------- K3: fused FF, M=64/block, 8 waves, double prefetch ----------------
// grid BT/64 = 256, block 512. Wave w = (mt = w&1, w4 = w>>1). Wave handles m-rows
// [r0+mt*32, +32) x j-cols [32*w4, +32) of each 128-j tile. mt-pair waves load
// identical weight frags (L1 absorbs the duplicate) -> L2 weight traffic halved.
// w1 AND w2 frags prefetched one jt ahead. shfl-exchange FF1->FF2 (no loop barriers).
__global__ __launch_bounds__(512, 2) void ff_ln_kernel(
    const bf16* __restrict__ h1b,
    const bf16* __restrict__ w1s, const float* __restrict__ b1,
    const bf16* __restrict__ w2s, const float* __restrict__ b2,
    const float* __restrict__ g2, const float* __restrict__ bt2,
    const float* __restrict__ gf, const float* __restrict__ btf,
    float* __restrict__ out){
    __shared__ float redp[2*3*3*1088];            // [mt][w4-1][ct] partials, stride-17 padded
    __shared__ float zt[96*65];                   // LN output transposed (64 tokens)
    const int tid = threadIdx.x;
    const int w = tid >> 6, lane = tid & 63;
    const int lm = lane & 31, hq = lane >> 5;
    const int mt = w & 1, w4 = w >> 1;
    const int r0 = blockIdx.x * 64;
    const int rr = r0 + mt*32;
    short8 hf[6];
    #pragma unroll
    for(int ks = 0; ks < 6; ++ks)
        hf[ks] = *(const short8*)((const short*)h1b
                   + (size_t)(rr + lm)*96 + ks*16 + hq*8);
    floatx16 acc2[3];
    #pragma unroll
    for(int i = 0; i < 3; ++i)
        #pragma unroll
        for(int r = 0; r < 16; ++r) acc2[i][r] = 0.f;

    const short* w1p = (const short*)w1s + (size_t)w4*6*512 + lane*8;
    const short* w2p = (const short*)w2s + (size_t)w4*2*3*512 + lane*8;
    short8 cw1[6], cw2[6];
    #pragma unroll
    for(int ks = 0; ks < 6; ++ks)
        cw1[ks] = *(const short8*)(w1p + ks*512);
    #pragma unroll
    for(int g = 0; g < 2; ++g)
        #pragma unroll
        for(int ct = 0; ct < 3; ++ct)
            cw2[g*3 + ct] = *(const short8*)(w2p + ((size_t)g*3 + ct)*512);

    #pragma unroll
    for(int jt = 0; jt < 16; ++jt){
        const int jn = (jt + 1) & 15;
        short8 nw1[6], nw2[6];
        #pragma unroll
        for(int ks = 0; ks < 6; ++ks)
            nw1[ks] = *(const short8*)(w1p + (size_t)jn*4*6*512 + ks*512);
        #pragma unroll
        for(int g = 0; g < 2; ++g)
            #pragma unroll
            for(int ct = 0; ct < 3; ++ct)
                nw2[g*3 + ct] = *(const short8*)(w2p + ((size_t)jn*4*2*3 + g*3 + ct)*512);
        // ---- FF1 (even/odd accumulator chains)
        floatx16 aA, aB;
        #pragma unroll
        for(int r = 0; r < 16; ++r){ aA[r] = 0.f; aB[r] = 0.f; }
        #pragma unroll
        for(int ks = 0; ks < 3; ++ks){
            aA = __builtin_amdgcn_mfma_f32_32x32x16_bf16(cw1[2*ks],   hf[2*ks],   aA, 0,0,0);
            aB = __builtin_amdgcn_mfma_f32_32x32x16_bf16(cw1[2*ks+1], hf[2*ks+1], aB, 0,0,0);
        }
        // ---- pack: bias + relu + bf16 (j-local = 8q+4hq+r within wave's 32 cols)
        int pk[4][2];
        #pragma unroll
        for(int q = 0; q < 4; ++q){
            float4 bv = *(const float4*)(b1 + jt*128 + w4*32 + 8*q + 4*hq);
            float bva[4] = {bv.x, bv.y, bv.z, bv.w};
            short4v t;
            #pragma unroll
            for(int r = 0; r < 4; ++r){
                float v = aA[4*q+r] + aB[4*q+r] + bva[r];
                t[r] = f2bs(v > 0.f ? v : 0.f);
            }
            int2 u = *(int2*)&t;
            pk[q][0] = u.x; pk[q][1] = u.y;
        }
        // ---- FF2: cross-hq exchange -> B-frag, accumulate
        #pragma unroll
        for(int g = 0; g < 2; ++g){
            int a0 = pk[2*g][0],   a1 = pk[2*g][1];
            int b0 = pk[2*g+1][0], b1v = pk[2*g+1][1];
            int ra0 = __shfl_xor(a0, 32),  ra1 = __shfl_xor(a1, 32);
            int rb0 = __shfl_xor(b0, 32),  rb1 = __shfl_xor(b1v, 32);
            int4 sfi;
            sfi.x = hq ? rb0 : a0;
            sfi.y = hq ? rb1 : a1;
            sfi.z = hq ? b0  : ra0;
            sfi.w = hq ? b1v : ra1;
            short8 sf = *(short8*)&sfi;
            #pragma unroll
            for(int ct = 0; ct < 3; ++ct)
                acc2[ct] = __builtin_amdgcn_mfma_f32_32x32x16_bf16(cw2[g*3+ct], sf, acc2[ct], 0,0,0);
        }
        #pragma unroll
        for(int ks = 0; ks < 6; ++ks) cw1[ks] = nw1[ks];
        #pragma unroll
        for(int i = 0; i < 6; ++i) cw2[i] = nw2[i];
    }
    // ---- epilogue: per-mt cross-wave reduce + b2 + residual + LN2 + LNf + transpose out
    __syncthreads();
    if(w4 > 0){
        #pragma unroll
        for(int ct = 0; ct < 3; ++ct)
            #pragma unroll
            for(int q = 0; q < 4; ++q)
                #pragma unroll
                for(int r = 0; r < 4; ++r)
                    redp[((mt*3 + (w4-1))*3 + ct)*1088 + lane*17 + 4*q + r] = acc2[ct][4*q+r];
    }
    __syncthreads();
    if(w4 == 0){
        float vals[48];
        float p1 = 0.f, p2 = 0.f;
        #pragma unroll
        for(int ct = 0; ct < 3; ++ct){
            #pragma unroll
            for(int q = 0; q < 4; ++q){
                int c = ct*32 + 8*q + 4*hq;
                float4 bv = *(const float4*)(b2 + c);
                short4v hv = *(const short4v*)((const short*)h1b + (size_t)(rr + lm)*96 + c);
                float bva[4] = {bv.x, bv.y, bv.z, bv.w};
                #pragma unroll
                for(int r = 0; r < 4; ++r){
                    float v = acc2[ct][4*q+r]
                            + redp[((mt*3 + 0)*3 + ct)*1088 + lane*17 + 4*q + r]
                            + redp[((mt*3 + 1)*3 + ct)*1088 + lane*17 + 4*q + r]
                            + redp[((mt*3 + 2)*3 + ct)*1088 + lane*17 + 4*q + r]
                            + bva[r] + bs2f(hv[r]);
                    vals[ct*16 + 4*q + r] = v;
                    p1 += v; p2 += v*v;
                }
            }
        }
        p1 += __shfl_xor(p1, 32);
        p2 += __shfl_xor(p2, 32);
        float mu = p1*(1.0f/96.0f);
        float rstd = rsqrtf(p2*(1.0f/96.0f) - mu*mu + 1e-5f);
        float q1 = 0.f, q2 = 0.f;
        #pragma unroll
        for(int ct = 0; ct < 3; ++ct){
            #pragma unroll
            for(int q = 0; q < 4; ++q){
                int c = ct*32 + 8*q + 4*hq;
                float4 gv = *(const float4*)(g2 + c);
                float4 bv = *(const float4*)(bt2 + c);
                float ga[4] = {gv.x, gv.y, gv.z, gv.w};
                float ba[4] = {bv.x, bv.y, bv.z, bv.w};
                #pragma unroll
                for(int r = 0; r < 4; ++r){
                    float y = (vals[ct*16+4*q+r] - mu)*rstd*ga[r] + ba[r];
                    vals[ct*16+4*q+r] = y;
                    q1 += y; q2 += y*y;
                }
            }
        }
        q1 += __shfl_xor(q1, 32);
        q2 += __shfl_xor(q2, 32);
        float mu2 = q1*(1.0f/96.0f);
        float rstd2 = rsqrtf(q2*(1.0f/96.0f) - mu2*mu2 + 1e-5f);
        #pragma unroll
        for(int ct = 0; ct < 3; ++ct){
            #pragma unroll
            for(int q = 0; q < 4; ++q){
                int c = ct*32 + 8*q + 4*hq;
                float4 gv = *(const float4*)(gf + c);
                float4 bv = *(const float4*)(btf + c);
                float ga[4] = {gv.x, gv.y, gv.z, gv.w};
                float ba[4] = {bv.x, bv.y, bv.z, bv.w};
                #pragma unroll
                for(int r = 0; r < 4; ++r)
                    zt[(c + r)*65 + mt*32 + lm] = (vals[ct*16+4*q+r] - mu2)*rstd2*ga[r] + ba[r];
            }
        }
    }
    __syncthreads();
    int bb  = r0 / T;
    int t0g = r0 % T;
    for(int e = tid; e < 96*64; e += 512){
        int c = e >> 6, tt = e & 63;
        out[(size_t)bb*C*T + (size_t)c*T + t0g + tt] = zt[c*65 + tt];
    }
}

extern "C" void kernel_launch(void* const* d_in, const int* in_sizes, int n_in,
                              void* d_out, int out_size, void* d_ws, size_t ws_size,
                              hipStream_t stream) {
    const float* x     = (const float*)d_in[0];
    const float* w_qkv = (const float*)d_in[1];
    const float* b_qkv = (const float*)d_in[2];
    const float* w_out = (const float*)d_in[3];
    const float* b_out = (const float*)d_in[4];
    const float* ln1_g = (const float*)d_in[5];
    const float* ln1_b = (const float*)d_in[6];
    const float* w_ff1 = (const float*)d_in[7];
    const float* b_ff1 = (const float*)d_in[8];
    const float* w_ff2 = (const float*)d_in[9];
    const float* b_ff2 = (const float*)d_in[10];
    const float* ln2_g = (const float*)d_in[11];
    const float* ln2_b = (const float*)d_in[12];
    const float* lnf_g = (const float*)d_in[13];
    const float* lnf_b = (const float*)d_in[14];
    float* out = (float*)d_out;

    // ws map (bytes), total 13.4 MB:
    //   qkvs [0, 9.44M)         Q/K/V [type][b][h][t][32] bf16
    //   h1b  [9.44M, 12.58M)    bf16 LN1 output
    //   wts  [12.58M, 13.44M)   bf16 weights (fragment-major)
    char* wsb = (char*)d_ws;
    bf16*  qkvs  = (bf16*)wsb;
    bf16*  h1b   = (bf16*)(wsb + 9437184);
    bf16*  wts   = (bf16*)(wsb + 12582912);
    bf16*  wqs   = wts;
    bf16*  wos   = wts + 27648;
    bf16*  w1s   = wts + 36864;
    bf16*  w2s   = wts + 233472;

    cvtw_kernel   <<<1680, 256, 0, stream>>>(w_qkv, w_out, w_ff1, w_ff2, wts);
    qkv_kernel    <<<BT/32, 256, 0, stream>>>(x, wqs, b_qkv, qkvs);
    attn_op_kernel<<<B*(T/64), 384, 0, stream>>>(qkvs, wos, b_out, x,
                                                 ln1_g, ln1_b, h1b);
    ff_ln_kernel  <<<BT/64, 512, 0, stream>>>(h1b, w1s, b_ff1, w2s, b_ff2,
                                              ln2_g, ln2_b, lnf_g, lnf_b, out);
}

// Round 12
// 126.167 us; speedup vs baseline: 1.2310x; 1.0035x over previous
//
#include <hip/hip_runtime.h>
#include <hip/hip_bf16.h>

#define B 8
#define T 2048
#define C 96
#define NH 3
#define HD 32
#define FFD 2048
#define HALF_W 32
#define BT (B*T)

typedef __hip_bfloat16 bf16;
typedef __attribute__((ext_vector_type(8))) short short8;
typedef __attribute__((ext_vector_type(4))) short short4v;
typedef __attribute__((ext_vector_type(16))) float floatx16;

__device__ __forceinline__ short f2bs(float v){
    __hip_bfloat16 h = __float2bfloat16(v);
    return *reinterpret_cast<short*>(&h);
}
__device__ __forceinline__ float bs2f(short s){
    unsigned u = ((unsigned)(unsigned short)s) << 16;
    return __uint_as_float(u);
}
__device__ __forceinline__ int imin(int a, int b){ return a < b ? a : b; }
__device__ __forceinline__ int imax(int a, int b){ return a > b ? a : b; }
__device__ __forceinline__ short8 ld_b64x2(const short* p){
    short4v a = *(const short4v*)p;
    short4v b = *(const short4v*)(p + 4);
    short8 v;
    v[0]=a[0]; v[1]=a[1]; v[2]=a[2]; v[3]=a[3];
    v[4]=b[0]; v[5]=b[1]; v[6]=b[2]; v[7]=b[3];
    return v;
}

// ---------------- K0: convert weights to bf16 in FRAGMENT-MAJOR (swizzled) layout ----
//   wq : [ot 0..8][ks 0..5][lane][8]                      27648
//   wo : [ct 0..2][ks 0..5][lane][8]                       9216
//   w1 : [jt 0..15][w4 0..3][ks 0..5][lane][8]           196608
//   w2 : [jt 0..15][w4 0..3][g 0..1][ct 0..2][lane][8]   196608
__global__ void cvtw_kernel(const float* __restrict__ wq, const float* __restrict__ wo,
                            const float* __restrict__ w1, const float* __restrict__ w2,
                            bf16* __restrict__ dst){
    int i = blockIdx.x*256 + threadIdx.x;
    if(i < 27648){
        int e = i&7, lane = (i>>3)&63, r = i>>9;
        int ks = r%6, ot = r/6;
        int o = ot*32 + (lane&31);
        int k = ks*16 + (lane>>5)*8 + e;
        dst[i] = __float2bfloat16(wq[o*96 + k]);
    } else if(i < 36864){
        int j = i - 27648;
        int e = j&7, lane = (j>>3)&63, r = j>>9;
        int ks = r%6, ct = r/6;
        int c = ct*32 + (lane&31);
        int k = ks*16 + (lane>>5)*8 + e;
        dst[i] = __float2bfloat16(wo[c*96 + k]);
    } else if(i < 233472){
        int j = i - 36864;
        int e = j&7, lane = (j>>3)&63, r = j>>9;
        int ks = r%6; r /= 6;
        int w = r%4, jt = r/4;
        int row = jt*128 + w*32 + (lane&31);
        int k = ks*16 + (lane>>5)*8 + e;
        dst[i] = __float2bfloat16(w1[row*96 + k]);
    } else if(i < 430080){
        int j = i - 233472;
        int e = j&7, lane = (j>>3)&63, r = j>>9;
        int ct = r%3; r /= 3;
        int g = r%2; r /= 2;
        int w = r%4, jt = r/4;
        int c = ct*32 + (lane&31);
        int k = jt*128 + w*32 + g*16 + (lane>>5)*8 + e;
        dst[i] = __float2bfloat16(w2[c*FFD + k]);
    }
}

// ---------------- K1: QKV projection, MFMA; Q/K/V stored [type][b][h][t][32] ----------------
__global__ __launch_bounds__(256) void qkv_kernel(
    const float* __restrict__ x, const bf16* __restrict__ wqs,
    const float* __restrict__ bias, bf16* __restrict__ qkvs){
    __shared__ float xs[96*36];
    int b  = blockIdx.x >> 6;
    int t0 = (blockIdx.x & 63) * 32;
    for(int e = threadIdx.x; e < 96*8; e += 256){
        int c = e >> 3, t4 = e & 7;
        *(float4*)(xs + c*36 + t4*4) =
            *(const float4*)(x + (size_t)b*C*T + (size_t)c*T + t0 + t4*4);
    }
    __syncthreads();
    int r0 = b*T + t0;
    const int w = threadIdx.x >> 6, lane = threadIdx.x & 63;
    const int lm = lane & 31, hq = lane >> 5;
    short8 bfr[6];
    #pragma unroll
    for(int ks = 0; ks < 6; ++ks){
        short8 v;
        #pragma unroll
        for(int i = 0; i < 8; ++i)
            v[i] = f2bs(xs[(ks*16 + hq*8 + i)*36 + lm]);
        bfr[ks] = v;
    }
    int nacc = (w == 0) ? 3 : 2;
    int ots[3] = {w, w+4, 8};
    floatx16 acc[3];
    #pragma unroll
    for(int i = 0; i < 3; ++i)
        #pragma unroll
        for(int r = 0; r < 16; ++r) acc[i][r] = 0.f;
    #pragma unroll
    for(int i = 0; i < 3; ++i){
        if(i < nacc){
            #pragma unroll
            for(int ks = 0; ks < 6; ++ks){
                short8 af = *(const short8*)((const short*)wqs
                              + (size_t)(ots[i]*6 + ks)*512 + lane*8);
                acc[i] = __builtin_amdgcn_mfma_f32_32x32x16_bf16(af, bfr[ks], acc[i], 0,0,0);
            }
        }
    }
    #pragma unroll
    for(int i = 0; i < 3; ++i){
        if(i < nacc){
            int type = ots[i]/3, hh = ots[i]%3;
            size_t rowbase = (((size_t)type*B*NH) + (size_t)b*NH + hh)*T + t0 + lm;
            #pragma unroll
            for(int q = 0; q < 4; ++q){
                float4 bv = *(const float4*)(bias + ots[i]*32 + 8*q + 4*hq);
                short4v pk;
                pk[0] = f2bs(acc[i][4*q+0] + bv.x);
                pk[1] = f2bs(acc[i][4*q+1] + bv.y);
                pk[2] = f2bs(acc[i][4*q+2] + bv.z);
                pk[3] = f2bs(acc[i][4*q+3] + bv.w);
                *(short4v*)((short*)qkvs + rowbase*32 + 8*q + 4*hq) = pk;
            }
        }
    }
}

// ---------------- K2: FUSED attention + outproj + residual + LN1, 32-token blocks ----
// grid B*(T/32)=512, block 192 (3 waves). Phase A: wave = head h, 32 queries.
// Phase B: wave = ct. 46 KB LDS -> 2 blocks/CU for cross-block phase overlap.
__global__ __launch_bounds__(192) void attn_op_kernel(
    const bf16* __restrict__ qkvs, const bf16* __restrict__ wos,
    const float* __restrict__ bias, const float* __restrict__ x,
    const float* __restrict__ g1, const float* __restrict__ bb1,
    bf16* __restrict__ h1b){
    __shared__ __align__(16) short VtS[3*3200];     // per head: V^T [d 32][key 0..95] s100
    __shared__ __align__(16) short PtS[3][3200];    // per wave: P [query 32][key 0..95] s100
    __shared__ float LsS[3][32];
    __shared__ __align__(16) short ctxS[32*100];    // ctx [token][c] stride 100
    __shared__ float red1[2][3][32];
    const int tid = threadIdx.x;
    const int w = tid / 64, lane = tid & 63;
    const int lm = lane & 31, hq = lane >> 5;
    int b  = blockIdx.x >> 6;            // T/32 = 64 tiles per batch
    int t0 = (blockIdx.x & 63) * 32;

    // preload phase-B weight fragments (ct = w), consumed after 2 barriers
    short8 wof[6];
    #pragma unroll
    for(int ks = 0; ks < 6; ++ks)
        wof[ks] = *(const short8*)((const short*)wos + (size_t)(w*6 + ks)*512 + lane*8);

    // ---- stage V^T for all 3 heads: keys t0-32 .. t0+63 (96)
    for(int e = tid; e < 576; e += 192){
        int hh = e / 192, rem = e % 192;
        int kp = rem >> 2, d8 = rem & 3;       // key pair 2kp,2kp+1; dims d8*8..+8
        const short* vb = (const short*)qkvs + ((size_t)2*B*NH + (size_t)b*NH + hh)*T*32;
        int sa = imin(imax(t0 - 32 + 2*kp, 0), T-1);
        int sb = imin(imax(t0 - 32 + 2*kp + 1, 0), T-1);
        short8 va = *(const short8*)(vb + (size_t)sa*32 + d8*8);
        short8 v2 = *(const short8*)(vb + (size_t)sb*32 + d8*8);
        #pragma unroll
        for(int j = 0; j < 8; ++j){
            int val = (int)(unsigned short)va[j] | ((int)(unsigned short)v2[j] << 16);
            *(int*)(VtS + hh*3200 + (d8*8 + j)*100 + 2*kp) = val;
        }
    }
    // ---- S phase: queries t0+lm, head w
    const short* qb = (const short*)qkvs + ((size_t)0*B*NH + (size_t)b*NH + w)*T*32;
    const short* kb = (const short*)qkvs + ((size_t)1*B*NH + (size_t)b*NH + w)*T*32;
    short8 qf0, qf1;
    {
        const short* qrow = qb + (size_t)(t0 + lm)*32;
        qf0 = *(const short8*)(qrow + hq*8);
        qf1 = *(const short8*)(qrow + 16 + hq*8);
    }
    floatx16 S[3];
    #pragma unroll
    for(int sub = 0; sub < 3; ++sub){
        int srow = imin(imax(t0 - 32 + sub*32 + lm, 0), T-1);
        const short* krow = kb + (size_t)srow*32;
        short8 kf0 = *(const short8*)(krow + hq*8);
        short8 kf1 = *(const short8*)(krow + 16 + hq*8);
        floatx16 z;
        #pragma unroll
        for(int r = 0; r < 16; ++r) z[r] = 0.f;
        z = __builtin_amdgcn_mfma_f32_32x32x16_bf16(kf0, qf0, z, 0,0,0);
        z = __builtin_amdgcn_mfma_f32_32x32x16_bf16(kf1, qf1, z, 0,0,0);
        S[sub] = z;
    }
    const float scale = 0.17677669529663687f;
    float part = 0.f;
    #pragma unroll
    for(int sub = 0; sub < 3; ++sub){
        #pragma unroll
        for(int r = 0; r < 16; ++r){
            int key_local = sub*32 + (r&3) + 8*(r>>2) + 4*hq;
            int s_glob = t0 - 32 + key_local;
            int rel = key_local - lm;
            bool ok = (rel >= 0) && (rel <= 64) && (s_glob >= 0) && (s_glob < T);
            float p = ok ? __expf(S[sub][r]*scale) : 0.f;
            S[sub][r] = p;
            part += p;
        }
    }
    float ltot = part + __shfl_xor(part, 32);
    if(hq == 0) LsS[w][lm] = ltot;
    #pragma unroll
    for(int sub = 0; sub < 3; ++sub){
        #pragma unroll
        for(int q4 = 0; q4 < 4; ++q4){
            int kbase = sub*32 + 8*q4 + 4*hq;
            short4v pk;
            pk[0] = f2bs(S[sub][4*q4+0]);
            pk[1] = f2bs(S[sub][4*q4+1]);
            pk[2] = f2bs(S[sub][4*q4+2]);
            pk[3] = f2bs(S[sub][4*q4+3]);
            *(short4v*)(PtS[w] + lm*100 + kbase) = pk;
        }
    }
    __syncthreads();   // VtS ready (PtS is same-wave)
    // ---- PV
    floatx16 O;
    #pragma unroll
    for(int r = 0; r < 16; ++r) O[r] = 0.f;
    #pragma unroll
    for(int ks = 0; ks < 6; ++ks){
        short8 pa = ld_b64x2(PtS[w] + lm*100 + ks*16 + hq*8);
        short8 vf = ld_b64x2(VtS + w*3200 + lm*100 + ks*16 + hq*8);
        O = __builtin_amdgcn_mfma_f32_32x32x16_bf16(pa, vf, O, 0,0,0);
    }
    #pragma unroll
    for(int r = 0; r < 16; ++r){
        int qr = (r&3) + 8*(r>>2) + 4*hq;
        float linv = 1.f / LsS[w][qr];
        ctxS[qr*100 + w*32 + lm] = f2bs(O[r]*linv);
    }
    __syncthreads();   // ctxS ready

    // ======== Phase B: outproj + residual + LN1 (wave = ct = w) ========
    short8 bfr[6];
    #pragma unroll
    for(int ks = 0; ks < 6; ++ks)
        bfr[ks] = ld_b64x2(ctxS + lm*100 + ks*16 + hq*8);
    floatx16 acc;
    #pragma unroll
    for(int r = 0; r < 16; ++r) acc[r] = 0.f;
    #pragma unroll
    for(int ks = 0; ks < 6; ++ks)
        acc = __builtin_amdgcn_mfma_f32_32x32x16_bf16(wof[ks], bfr[ks], acc, 0,0,0);
    float vals[16];
    float p1 = 0.f, p2 = 0.f;
    #pragma unroll
    for(int q = 0; q < 4; ++q){
        int c = w*32 + 8*q + 4*hq;
        float4 bv = *(const float4*)(bias + c);
        float bva[4] = {bv.x, bv.y, bv.z, bv.w};
        #pragma unroll
        for(int r = 0; r < 4; ++r){
            float xv = x[(size_t)b*C*T + (size_t)(c + r)*T + t0 + lm];
            float v = acc[4*q+r] + bva[r] + xv;
            vals[4*q+r] = v;
            p1 += v; p2 += v*v;
        }
    }
    p1 += __shfl_xor(p1, 32);
    p2 += __shfl_xor(p2, 32);
    if(hq == 0){ red1[0][w][lm] = p1; red1[1][w][lm] = p2; }
    __syncthreads();
    float s  = red1[0][0][lm] + red1[0][1][lm] + red1[0][2][lm];
    float s2 = red1[1][0][lm] + red1[1][1][lm] + red1[1][2][lm];
    float mu = s * (1.0f/96.0f);
    float rstd = rsqrtf(s2*(1.0f/96.0f) - mu*mu + 1e-5f);
    int row = b*T + t0 + lm;
    #pragma unroll
    for(int q = 0; q < 4; ++q){
        int c = w*32 + 8*q + 4*hq;
        float4 gv = *(const float4*)(g1 + c);
        float4 bv = *(const float4*)(bb1 + c);
        float ga[4] = {gv.x, gv.y, gv.z, gv.w};
        float ba[4] = {bv.x, bv.y, bv.z, bv.w};
        short4v pk;
        #pragma unroll
        for(int r = 0; r < 4; ++r)
            pk[r] = f2bs((vals[4*q+r] - mu)*rstd*ga[r] + ba[r]);
        *(short4v*)((short*)h1b + (size_t)row*96 + c) = pk;
    }
}

// ---------------- K3: fused FF, mt-shared weights (2 MFMAs per fragment) ----------------
// grid BT/64 = 256, block 256 (4 waves = j-quarters). Each wave handles BOTH m-tiles:
// weight fragment loads halve (12k lines/CU), per-wave ILP doubles (24 MFMA/iter).
// 1 wave/SIMD; ~320 VGPRs fit the 512 budget at launch_bounds(256,1).
__global__ __launch_bounds__(256, 1) void ff_ln_kernel(
    const bf16* __restrict__ h1b,
    const bf16* __restrict__ w1s, const float* __restrict__ b1,
    const bf16* __restrict__ w2s, const float* __restrict__ b2,
    const float* __restrict__ g2, const float* __restrict__ bt2,
    const float* __restrict__ gf, const float* __restrict__ btf,
    float* __restrict__ out){
    __shared__ float redp[4*2*3*1088];            // [w4][mt][ct], stride-17 padded (104 KB)
    __shared__ float zt[96*65];                   // LN output transposed (64 tokens)
    const int tid = threadIdx.x;
    const int w4 = tid >> 6, lane = tid & 63;
    const int lm = lane & 31, hq = lane >> 5;
    const int r0 = blockIdx.x * 64;
    short8 hf[2][6];
    #pragma unroll
    for(int mt = 0; mt < 2; ++mt)
        #pragma unroll
        for(int ks = 0; ks < 6; ++ks)
            hf[mt][ks] = *(const short8*)((const short*)h1b
                       + (size_t)(r0 + mt*32 + lm)*96 + ks*16 + hq*8);
    floatx16 acc2[2][3];
    #pragma unroll
    for(int mt = 0; mt < 2; ++mt)
        #pragma unroll
        for(int i = 0; i < 3; ++i)
            #pragma unroll
            for(int r = 0; r < 16; ++r) acc2[mt][i][r] = 0.f;

    const short* w1p = (const short*)w1s + (size_t)w4*6*512 + lane*8;
    const short* w2p = (const short*)w2s + (size_t)w4*2*3*512 + lane*8;
    short8 cw1[6], cw2[6];
    #pragma unroll
    for(int ks = 0; ks < 6; ++ks)
        cw1[ks] = *(const short8*)(w1p + ks*512);
    #pragma unroll
    for(int g = 0; g < 2; ++g)
        #pragma unroll
        for(int ct = 0; ct < 3; ++ct)
            cw2[g*3 + ct] = *(const short8*)(w2p + ((size_t)g*3 + ct)*512);

    #pragma unroll
    for(int jt = 0; jt < 16; ++jt){
        const int jn = (jt + 1) & 15;
        short8 nw1[6], nw2[6];
        #pragma unroll
        for(int ks = 0; ks < 6; ++ks)
            nw1[ks] = *(const short8*)(w1p + (size_t)jn*4*6*512 + ks*512);
        #pragma unroll
        for(int g = 0; g < 2; ++g)
            #pragma unroll
            for(int ct = 0; ct < 3; ++ct)
                nw2[g*3 + ct] = *(const short8*)(w2p + ((size_t)jn*4*2*3 + g*3 + ct)*512);
        // ---- FF1: two interleaved chains (mt0, mt1) sharing cw1 fragments
        floatx16 a0, a1;
        #pragma unroll
        for(int r = 0; r < 16; ++r){ a0[r] = 0.f; a1[r] = 0.f; }
        #pragma unroll
        for(int ks = 0; ks < 6; ++ks){
            a0 = __builtin_amdgcn_mfma_f32_32x32x16_bf16(cw1[ks], hf[0][ks], a0, 0,0,0);
            a1 = __builtin_amdgcn_mfma_f32_32x32x16_bf16(cw1[ks], hf[1][ks], a1, 0,0,0);
        }
        // ---- pack both mt: bias + relu + bf16 int-pairs
        int pk[2][4][2];
        #pragma unroll
        for(int q = 0; q < 4; ++q){
            float4 bv = *(const float4*)(b1 + jt*128 + w4*32 + 8*q + 4*hq);
            float bva[4] = {bv.x, bv.y, bv.z, bv.w};
            short4v t0v, t1v;
            #pragma unroll
            for(int r = 0; r < 4; ++r){
                float v0 = a0[4*q+r] + bva[r];
                float v1 = a1[4*q+r] + bva[r];
                t0v[r] = f2bs(v0 > 0.f ? v0 : 0.f);
                t1v[r] = f2bs(v1 > 0.f ? v1 : 0.f);
            }
            int2 u0 = *(int2*)&t0v; int2 u1 = *(int2*)&t1v;
            pk[0][q][0] = u0.x; pk[0][q][1] = u0.y;
            pk[1][q][0] = u1.x; pk[1][q][1] = u1.y;
        }
        // ---- FF2: cross-hq exchange per mt -> B-frags, 12 MFMAs sharing cw2 frags
        #pragma unroll
        for(int g = 0; g < 2; ++g){
            short8 sf[2];
            #pragma unroll
            for(int mt = 0; mt < 2; ++mt){
                int a0i = pk[mt][2*g][0],   a1i = pk[mt][2*g][1];
                int b0i = pk[mt][2*g+1][0], b1i = pk[mt][2*g+1][1];
                int ra0 = __shfl_xor(a0i, 32), ra1 = __shfl_xor(a1i, 32);
                int rb0 = __shfl_xor(b0i, 32), rb1 = __shfl_xor(b1i, 32);
                int4 sfi;
                sfi.x = hq ? rb0 : a0i;
                sfi.y = hq ? rb1 : a1i;
                sfi.z = hq ? b0i : ra0;
                sfi.w = hq ? b1i : ra1;
                sf[mt] = *(short8*)&sfi;
            }
            #pragma unroll
            for(int ct = 0; ct < 3; ++ct){
                acc2[0][ct] = __builtin_amdgcn_mfma_f32_32x32x16_bf16(cw2[g*3+ct], sf[0], acc2[0][ct], 0,0,0);
                acc2[1][ct] = __builtin_amdgcn_mfma_f32_32x32x16_bf16(cw2[g*3+ct], sf[1], acc2[1][ct], 0,0,0);
            }
        }
        #pragma unroll
        for(int ks = 0; ks < 6; ++ks) cw1[ks] = nw1[ks];
        #pragma unroll
        for(int i = 0; i < 6; ++i) cw2[i] = nw2[i];
    }
    // ---- epilogue: all waves write partials; waves 0/1 finalize mt 0/1
    __syncthreads();
    #pragma unroll
    for(int mt = 0; mt < 2; ++mt)
        #pragma unroll
        for(int ct = 0; ct < 3; ++ct)
            #pragma unroll
            for(int q = 0; q < 4; ++q)
                #pragma unroll
                for(int r = 0; r < 4; ++r)
                    redp[((w4*2 + mt)*3 + ct)*1088 + lane*17 + 4*q + r] = acc2[mt][ct][4*q+r];
    __syncthreads();
    if(w4 < 2){
        const int mt = w4;
        const int rr = r0 + mt*32;
        float vals[48];
        float p1 = 0.f, p2 = 0.f;
        #pragma unroll
        for(int ct = 0; ct < 3; ++ct){
            #pragma unroll
            for(int q = 0; q < 4; ++q){
                int c = ct*32 + 8*q + 4*hq;
                float4 bv = *(const float4*)(b2 + c);
                short4v hv = *(const short4v*)((const short*)h1b + (size_t)(rr + lm)*96 + c);
                float bva[4] = {bv.x, bv.y, bv.z, bv.w};
                #pragma unroll
                for(int r = 0; r < 4; ++r){
                    float v = redp[((0*2 + mt)*3 + ct)*1088 + lane*17 + 4*q + r]
                            + redp[((1*2 + mt)*3 + ct)*1088 + lane*17 + 4*q + r]
                            + redp[((2*2 + mt)*3 + ct)*1088 + lane*17 + 4*q + r]
                            + redp[((3*2 + mt)*3 + ct)*1088 + lane*17 + 4*q + r]
                            + bva[r] + bs2f(hv[r]);
                    vals[ct*16 + 4*q + r] = v;
                    p1 += v; p2 += v*v;
                }
            }
        }
        p1 += __shfl_xor(p1, 32);
        p2 += __shfl_xor(p2, 32);
        float mu = p1*(1.0f/96.0f);
        float rstd = rsqrtf(p2*(1.0f/96.0f) - mu*mu + 1e-5f);
        float q1 = 0.f, q2 = 0.f;
        #pragma unroll
        for(int ct = 0; ct < 3; ++ct){
            #pragma unroll
            for(int q = 0; q < 4; ++q){
                int c = ct*32 + 8*q + 4*hq;
                float4 gv = *(const float4*)(g2 + c);
                float4 bv = *(const float4*)(bt2 + c);
                float ga[4] = {gv.x, gv.y, gv.z, gv.w};
                float ba[4] = {bv.x, bv.y, bv.z, bv.w};
                #pragma unroll
                for(int r = 0; r < 4; ++r){
                    float y = (vals[ct*16+4*q+r] - mu)*rstd*ga[r] + ba[r];
                    vals[ct*16+4*q+r] = y;
                    q1 += y; q2 += y*y;
                }
            }
        }
        q1 += __shfl_xor(q1, 32);
        q2 += __shfl_xor(q2, 32);
        float mu2 = q1*(1.0f/96.0f);
        float rstd2 = rsqrtf(q2*(1.0f/96.0f) - mu2*mu2 + 1e-5f);
        #pragma unroll
        for(int ct = 0; ct < 3; ++ct){
            #pragma unroll
            for(int q = 0; q < 4; ++q){
                int c = ct*32 + 8*q + 4*hq;
                float4 gv = *(const float4*)(gf + c);
                float4 bv = *(const float4*)(btf + c);
                float ga[4] = {gv.x, gv.y, gv.z, gv.w};
                float ba[4] = {bv.x, bv.y, bv.z, bv.w};
                #pragma unroll
                for(int r = 0; r < 4; ++r)
                    zt[(c + r)*65 + mt*32 + lm] = (vals[ct*16+4*q+r] - mu2)*rstd2*ga[r] + ba[r];
            }
        }
    }
    __syncthreads();
    int bb  = r0 / T;
    int t0g = r0 % T;
    for(int e = tid; e < 96*64; e += 256){
        int c = e >> 6, tt = e & 63;
        out[(size_t)bb*C*T + (size_t)c*T + t0g + tt] = zt[c*65 + tt];
    }
}

extern "C" void kernel_launch(void* const* d_in, const int* in_sizes, int n_in,
                              void* d_out, int out_size, void* d_ws, size_t ws_size,
                              hipStream_t stream) {
    const float* x     = (const float*)d_in[0];
    const float* w_qkv = (const float*)d_in[1];
    const float* b_qkv = (const float*)d_in[2];
    const float* w_out = (const float*)d_in[3];
    const float* b_out = (const float*)d_in[4];
    const float* ln1_g = (const float*)d_in[5];
    const float* ln1_b = (const float*)d_in[6];
    const float* w_ff1 = (const float*)d_in[7];
    const float* b_ff1 = (const float*)d_in[8];
    const float* w_ff2 = (const float*)d_in[9];
    const float* b_ff2 = (const float*)d_in[10];
    const float* ln2_g = (const float*)d_in[11];
    const float* ln2_b = (const float*)d_in[12];
    const float* lnf_g = (const float*)d_in[13];
    const float* lnf_b = (const float*)d_in[14];
    float* out = (float*)d_out;

    // ws map (bytes), total 13.4 MB:
    //   qkvs [0, 9.44M)         Q/K/V [type][b][h][t][32] bf16
    //   h1b  [9.44M, 12.58M)    bf16 LN1 output
    //   wts  [12.58M, 13.44M)   bf16 weights (fragment-major)
    char* wsb = (char*)d_ws;
    bf16*  qkvs  = (bf16*)wsb;
    bf16*  h1b   = (bf16*)(wsb + 9437184);
    bf16*  wts   = (bf16*)(wsb + 12582912);
    bf16*  wqs   = wts;
    bf16*  wos   = wts + 27648;
    bf16*  w1s   = wts + 36864;
    bf16*  w2s   = wts + 233472;

    cvtw_kernel   <<<1680, 256, 0, stream>>>(w_qkv, w_out, w_ff1, w_ff2, wts);
    qkv_kernel    <<<BT/32, 256, 0, stream>>>(x, wqs, b_qkv, qkvs);
    attn_op_kernel<<<B*(T/32), 192, 0, stream>>>(qkvs, wos, b_out, x,
                                                 ln1_g, ln1_b, h1b);
    ff_ln_kernel  <<<BT/64, 256, 0, stream>>>(h1b, w1s, b_ff1, w2s, b_ff2,
                                              ln2_g, ln2_b, lnf_g, lnf_b, out);
}

// Round 13
// 124.807 us; speedup vs baseline: 1.2444x; 1.0109x over previous
//
#include <hip/hip_runtime.h>
#include <hip/hip_bf16.h>

#define B 8
#define T 2048
#define C 96
#define NH 3
#define HD 32
#define FFD 2048
#define HALF_W 32
#define BT (B*T)

typedef __hip_bfloat16 bf16;
typedef __attribute__((ext_vector_type(8))) short short8;
typedef __attribute__((ext_vector_type(4))) short short4v;
typedef __attribute__((ext_vector_type(16))) float floatx16;

__device__ __forceinline__ short f2bs(float v){
    __hip_bfloat16 h = __float2bfloat16(v);
    return *reinterpret_cast<short*>(&h);
}
__device__ __forceinline__ float bs2f(short s){
    unsigned u = ((unsigned)(unsigned short)s) << 16;
    return __uint_as_float(u);
}
__device__ __forceinline__ int imin(int a, int b){ return a < b ? a : b; }
__device__ __forceinline__ int imax(int a, int b){ return a > b ? a : b; }
__device__ __forceinline__ short8 ld_b64x2(const short* p){
    short4v a = *(const short4v*)p;
    short4v b = *(const short4v*)(p + 4);
    short8 v;
    v[0]=a[0]; v[1]=a[1]; v[2]=a[2]; v[3]=a[3];
    v[4]=b[0]; v[5]=b[1]; v[6]=b[2]; v[7]=b[3];
    return v;
}

// ---------------- K0: convert weights to bf16 in FRAGMENT-MAJOR (swizzled) layout ----
__global__ void cvtw_kernel(const float* __restrict__ wq, const float* __restrict__ wo,
                            const float* __restrict__ w1, const float* __restrict__ w2,
                            bf16* __restrict__ dst){
    int i = blockIdx.x*256 + threadIdx.x;
    if(i < 27648){
        int e = i&7, lane = (i>>3)&63, r = i>>9;
        int ks = r%6, ot = r/6;
        int o = ot*32 + (lane&31);
        int k = ks*16 + (lane>>5)*8 + e;
        dst[i] = __float2bfloat16(wq[o*96 + k]);
    } else if(i < 36864){
        int j = i - 27648;
        int e = j&7, lane = (j>>3)&63, r = j>>9;
        int ks = r%6, ct = r/6;
        int c = ct*32 + (lane&31);
        int k = ks*16 + (lane>>5)*8 + e;
        dst[i] = __float2bfloat16(wo[c*96 + k]);
    } else if(i < 233472){
        int j = i - 36864;
        int e = j&7, lane = (j>>3)&63, r = j>>9;
        int ks = r%6; r /= 6;
        int w = r%4, jt = r/4;
        int row = jt*128 + w*32 + (lane&31);
        int k = ks*16 + (lane>>5)*8 + e;
        dst[i] = __float2bfloat16(w1[row*96 + k]);
    } else if(i < 430080){
        int j = i - 233472;
        int e = j&7, lane = (j>>3)&63, r = j>>9;
        int ct = r%3; r /= 3;
        int g = r%2; r /= 2;
        int w = r%4, jt = r/4;
        int c = ct*32 + (lane&31);
        int k = jt*128 + w*32 + g*16 + (lane>>5)*8 + e;
        dst[i] = __float2bfloat16(w2[c*FFD + k]);
    }
}

// ---------------- K1: QKV projection, MFMA ----------------
// Q,K stored FRAGMENT-MAJOR: [b][h][tile 0..63][ks 0..1][lane][8]  (coalesced stores)
// V stored row-major [b][h][t][32] (its staging in attn is already line-covered).
__global__ __launch_bounds__(256) void qkv_kernel(
    const float* __restrict__ x, const bf16* __restrict__ wqs,
    const float* __restrict__ bias, bf16* __restrict__ qswz,
    bf16* __restrict__ kswz, bf16* __restrict__ vbuf){
    __shared__ float xs[96*36];
    int b  = blockIdx.x >> 6;
    int tt = blockIdx.x & 63;            // token tile
    int t0 = tt * 32;
    for(int e = threadIdx.x; e < 96*8; e += 256){
        int c = e >> 3, t4 = e & 7;
        *(float4*)(xs + c*36 + t4*4) =
            *(const float4*)(x + (size_t)b*C*T + (size_t)c*T + t0 + t4*4);
    }
    __syncthreads();
    const int w = threadIdx.x >> 6, lane = threadIdx.x & 63;
    const int lm = lane & 31, hq = lane >> 5;
    short8 bfr[6];
    #pragma unroll
    for(int ks = 0; ks < 6; ++ks){
        short8 v;
        #pragma unroll
        for(int i = 0; i < 8; ++i)
            v[i] = f2bs(xs[(ks*16 + hq*8 + i)*36 + lm]);
        bfr[ks] = v;
    }
    int nacc = (w == 0) ? 3 : 2;
    int ots[3] = {w, w+4, 8};
    floatx16 acc[3];
    #pragma unroll
    for(int i = 0; i < 3; ++i)
        #pragma unroll
        for(int r = 0; r < 16; ++r) acc[i][r] = 0.f;
    #pragma unroll
    for(int i = 0; i < 3; ++i){
        if(i < nacc){
            #pragma unroll
            for(int ks = 0; ks < 6; ++ks){
                short8 af = *(const short8*)((const short*)wqs
                              + (size_t)(ots[i]*6 + ks)*512 + lane*8);
                acc[i] = __builtin_amdgcn_mfma_f32_32x32x16_bf16(af, bfr[ks], acc[i], 0,0,0);
            }
        }
    }
    // D: col=lm=token, reg->channel. Pack bias+bf16, then route per type.
    #pragma unroll
    for(int i = 0; i < 3; ++i){
        if(i < nacc){
            int ot = ots[i];
            int pkq[4][2];
            #pragma unroll
            for(int q = 0; q < 4; ++q){
                float4 bv = *(const float4*)(bias + ot*32 + 8*q + 4*hq);
                short4v t;
                t[0] = f2bs(acc[i][4*q+0] + bv.x);
                t[1] = f2bs(acc[i][4*q+1] + bv.y);
                t[2] = f2bs(acc[i][4*q+2] + bv.z);
                t[3] = f2bs(acc[i][4*q+3] + bv.w);
                int2 u = *(int2*)&t;
                pkq[q][0] = u.x; pkq[q][1] = u.y;
            }
            if(ot < 6){
                // Q (type 0) / K (type 1): cross-hq exchange -> fragment-major store
                int type = ot/3, hh = ot%3;
                short* base = (short*)(type == 0 ? qswz : kswz)
                            + ((size_t)(b*NH + hh)*64 + tt)*1024 + lane*8;
                #pragma unroll
                for(int g = 0; g < 2; ++g){
                    int a0 = pkq[2*g][0],   a1 = pkq[2*g][1];
                    int b0 = pkq[2*g+1][0], b1v = pkq[2*g+1][1];
                    int ra0 = __shfl_xor(a0, 32),  ra1 = __shfl_xor(a1, 32);
                    int rb0 = __shfl_xor(b0, 32),  rb1 = __shfl_xor(b1v, 32);
                    int4 sfi;
                    sfi.x = hq ? rb0 : a0;
                    sfi.y = hq ? rb1 : a1;
                    sfi.z = hq ? b0  : ra0;
                    sfi.w = hq ? b1v : ra1;
                    *(int4*)(base + g*512) = sfi;
                }
            } else {
                int hh = ot - 6;
                short* rowp = (short*)vbuf + ((size_t)(b*NH + hh)*T + t0 + lm)*32;
                #pragma unroll
                for(int q = 0; q < 4; ++q){
                    int2 u; u.x = pkq[q][0]; u.y = pkq[q][1];
                    *(int2*)(rowp + 8*q + 4*hq) = u;
                }
            }
        }
    }
}

// ---------------- K2: FUSED attention + outproj + residual + LN1, 32-token blocks ----
// grid B*(T/32)=512, block 192 (3 waves). Phase A: wave = head h, 32 queries.
// Q/K fragment loads are now COALESCED (fragment-major layout from qkv).
__global__ __launch_bounds__(192) void attn_op_kernel(
    const bf16* __restrict__ qswz, const bf16* __restrict__ kswz,
    const bf16* __restrict__ vbuf, const bf16* __restrict__ wos,
    const float* __restrict__ bias, const float* __restrict__ x,
    const float* __restrict__ g1, const float* __restrict__ bb1,
    bf16* __restrict__ h1b){
    __shared__ __align__(16) short VtS[3*3200];     // per head: V^T [d 32][key 0..95] s100
    __shared__ __align__(16) short PtS[3][3200];    // per wave: P [query 32][key 0..95] s100
    __shared__ float LsS[3][32];
    __shared__ __align__(16) short ctxS[32*100];    // ctx [token][c] stride 100
    __shared__ float red1[2][3][32];
    const int tid = threadIdx.x;
    const int w = tid / 64, lane = tid & 63;
    const int lm = lane & 31, hq = lane >> 5;
    int b  = blockIdx.x >> 6;
    int tt = blockIdx.x & 63;
    int t0 = tt * 32;

    // preload phase-B weight fragments (ct = w), consumed after 2 barriers
    short8 wof[6];
    #pragma unroll
    for(int ks = 0; ks < 6; ++ks)
        wof[ks] = *(const short8*)((const short*)wos + (size_t)(w*6 + ks)*512 + lane*8);

    // ---- stage V^T for all 3 heads: keys t0-32 .. t0+63 (96)
    for(int e = tid; e < 576; e += 192){
        int hh = e / 192, rem = e % 192;
        int kp = rem >> 2, d8 = rem & 3;
        const short* vb = (const short*)vbuf + (size_t)(b*NH + hh)*T*32;
        int sa = imin(imax(t0 - 32 + 2*kp, 0), T-1);
        int sb = imin(imax(t0 - 32 + 2*kp + 1, 0), T-1);
        short8 va = *(const short8*)(vb + (size_t)sa*32 + d8*8);
        short8 v2 = *(const short8*)(vb + (size_t)sb*32 + d8*8);
        #pragma unroll
        for(int j = 0; j < 8; ++j){
            int val = (int)(unsigned short)va[j] | ((int)(unsigned short)v2[j] << 16);
            *(int*)(VtS + hh*3200 + (d8*8 + j)*100 + 2*kp) = val;
        }
    }
    // ---- S phase: queries t0+lm, head w. Coalesced fragment loads.
    const short* qsw = (const short*)qswz + ((size_t)(b*NH + w)*64 + tt)*1024 + lane*8;
    short8 qf0 = *(const short8*)(qsw);
    short8 qf1 = *(const short8*)(qsw + 512);
    floatx16 S[3];
    #pragma unroll
    for(int sub = 0; sub < 3; ++sub){
        int kt = imin(imax(tt - 1 + sub, 0), 63);   // clamped tile; OOB keys masked below
        const short* ksw = (const short*)kswz + ((size_t)(b*NH + w)*64 + kt)*1024 + lane*8;
        short8 kf0 = *(const short8*)(ksw);
        short8 kf1 = *(const short8*)(ksw + 512);
        floatx16 z;
        #pragma unroll
        for(int r = 0; r < 16; ++r) z[r] = 0.f;
        z = __builtin_amdgcn_mfma_f32_32x32x16_bf16(kf0, qf0, z, 0,0,0);
        z = __builtin_amdgcn_mfma_f32_32x32x16_bf16(kf1, qf1, z, 0,0,0);
        S[sub] = z;
    }
    const float scale = 0.17677669529663687f;
    float part = 0.f;
    #pragma unroll
    for(int sub = 0; sub < 3; ++sub){
        #pragma unroll
        for(int r = 0; r < 16; ++r){
            int key_local = sub*32 + (r&3) + 8*(r>>2) + 4*hq;
            int s_glob = t0 - 32 + key_local;
            int rel = key_local - lm;
            bool ok = (rel >= 0) && (rel <= 64) && (s_glob >= 0) && (s_glob < T);
            float p = ok ? __expf(S[sub][r]*scale) : 0.f;
            S[sub][r] = p;
            part += p;
        }
    }
    float ltot = part + __shfl_xor(part, 32);
    if(hq == 0) LsS[w][lm] = ltot;
    #pragma unroll
    for(int sub = 0; sub < 3; ++sub){
        #pragma unroll
        for(int q4 = 0; q4 < 4; ++q4){
            int kbase = sub*32 + 8*q4 + 4*hq;
            short4v pk;
            pk[0] = f2bs(S[sub][4*q4+0]);
            pk[1] = f2bs(S[sub][4*q4+1]);
            pk[2] = f2bs(S[sub][4*q4+2]);
            pk[3] = f2bs(S[sub][4*q4+3]);
            *(short4v*)(PtS[w] + lm*100 + kbase) = pk;
        }
    }
    __syncthreads();   // VtS ready (PtS is same-wave)
    // ---- PV
    floatx16 O;
    #pragma unroll
    for(int r = 0; r < 16; ++r) O[r] = 0.f;
    #pragma unroll
    for(int ks = 0; ks < 6; ++ks){
        short8 pa = ld_b64x2(PtS[w] + lm*100 + ks*16 + hq*8);
        short8 vf = ld_b64x2(VtS + w*3200 + lm*100 + ks*16 + hq*8);
        O = __builtin_amdgcn_mfma_f32_32x32x16_bf16(pa, vf, O, 0,0,0);
    }
    #pragma unroll
    for(int r = 0; r < 16; ++r){
        int qr = (r&3) + 8*(r>>2) + 4*hq;
        float linv = 1.f / LsS[w][qr];
        ctxS[qr*100 + w*32 + lm] = f2bs(O[r]*linv);
    }
    __syncthreads();   // ctxS ready

    // ======== Phase B: outproj + residual + LN1 (wave = ct = w) ========
    short8 bfr[6];
    #pragma unroll
    for(int ks = 0; ks < 6; ++ks)
        bfr[ks] = ld_b64x2(ctxS + lm*100 + ks*16 + hq*8);
    floatx16 acc;
    #pragma unroll
    for(int r = 0; r < 16; ++r) acc[r] = 0.f;
    #pragma unroll
    for(int ks = 0; ks < 6; ++ks)
        acc = __builtin_amdgcn_mfma_f32_32x32x16_bf16(wof[ks], bfr[ks], acc, 0,0,0);
    float vals[16];
    float p1 = 0.f, p2 = 0.f;
    #pragma unroll
    for(int q = 0; q < 4; ++q){
        int c = w*32 + 8*q + 4*hq;
        float4 bv = *(const float4*)(bias + c);
        float bva[4] = {bv.x, bv.y, bv.z, bv.w};
        #pragma unroll
        for(int r = 0; r < 4; ++r){
            float xv = x[(size_t)b*C*T + (size_t)(c + r)*T + t0 + lm];
            float v = acc[4*q+r] + bva[r] + xv;
            vals[4*q+r] = v;
            p1 += v; p2 += v*v;
        }
    }
    p1 += __shfl_xor(p1, 32);
    p2 += __shfl_xor(p2, 32);
    if(hq == 0){ red1[0][w][lm] = p1; red1[1][w][lm] = p2; }
    __syncthreads();
    float s  = red1[0][0][lm] + red1[0][1][lm] + red1[0][2][lm];
    float s2 = red1[1][0][lm] + red1[1][1][lm] + red1[1][2][lm];
    float mu = s * (1.0f/96.0f);
    float rstd = rsqrtf(s2*(1.0f/96.0f) - mu*mu + 1e-5f);
    int row = b*T + t0 + lm;
    #pragma unroll
    for(int q = 0; q < 4; ++q){
        int c = w*32 + 8*q + 4*hq;
        float4 gv = *(const float4*)(g1 + c);
        float4 bv = *(const float4*)(bb1 + c);
        float ga[4] = {gv.x, gv.y, gv.z, gv.w};
        float ba[4] = {bv.x, bv.y, bv.z, bv.w};
        short4v pk;
        #pragma unroll
        for(int r = 0; r < 4; ++r)
            pk[r] = f2bs((vals[4*q+r] - mu)*rstd*ga[r] + ba[r]);
        *(short4v*)((short*)h1b + (size_t)row*96 + c) = pk;
    }
}

// ---------------- K3: fused FF, mt-shared weights (2 MFMAs per fragment) ----------------
__global__ __launch_bounds__(256, 1) void ff_ln_kernel(
    const bf16* __restrict__ h1b,
    const bf16* __restrict__ w1s, const float* __restrict__ b1,
    const bf16* __restrict__ w2s, const float* __restrict__ b2,
    const float* __restrict__ g2, const float* __restrict__ bt2,
    const float* __restrict__ gf, const float* __restrict__ btf,
    float* __restrict__ out){
    __shared__ float redp[4*2*3*1088];
    __shared__ float zt[96*65];
    const int tid = threadIdx.x;
    const int w4 = tid >> 6, lane = tid & 63;
    const int lm = lane & 31, hq = lane >> 5;
    const int r0 = blockIdx.x * 64;
    short8 hf[2][6];
    #pragma unroll
    for(int mt = 0; mt < 2; ++mt)
        #pragma unroll
        for(int ks = 0; ks < 6; ++ks)
            hf[mt][ks] = *(const short8*)((const short*)h1b
                       + (size_t)(r0 + mt*32 + lm)*96 + ks*16 + hq*8);
    floatx16 acc2[2][3];
    #pragma unroll
    for(int mt = 0; mt < 2; ++mt)
        #pragma unroll
        for(int i = 0; i < 3; ++i)
            #pragma unroll
            for(int r = 0; r < 16; ++r) acc2[mt][i][r] = 0.f;

    const short* w1p = (const short*)w1s + (size_t)w4*6*512 + lane*8;
    const short* w2p = (const short*)w2s + (size_t)w4*2*3*512 + lane*8;
    short8 cw1[6], cw2[6];
    #pragma unroll
    for(int ks = 0; ks < 6; ++ks)
        cw1[ks] = *(const short8*)(w1p + ks*512);
    #pragma unroll
    for(int g = 0; g < 2; ++g)
        #pragma unroll
        for(int ct = 0; ct < 3; ++ct)
            cw2[g*3 + ct] = *(const short8*)(w2p + ((size_t)g*3 + ct)*512);

    #pragma unroll
    for(int jt = 0; jt < 16; ++jt){
        const int jn = (jt + 1) & 15;
        short8 nw1[6], nw2[6];
        #pragma unroll
        for(int ks = 0; ks < 6; ++ks)
            nw1[ks] = *(const short8*)(w1p + (size_t)jn*4*6*512 + ks*512);
        #pragma unroll
        for(int g = 0; g < 2; ++g)
            #pragma unroll
            for(int ct = 0; ct < 3; ++ct)
                nw2[g*3 + ct] = *(const short8*)(w2p + ((size_t)jn*4*2*3 + g*3 + ct)*512);
        floatx16 a0, a1;
        #pragma unroll
        for(int r = 0; r < 16; ++r){ a0[r] = 0.f; a1[r] = 0.f; }
        #pragma unroll
        for(int ks = 0; ks < 6; ++ks){
            a0 = __builtin_amdgcn_mfma_f32_32x32x16_bf16(cw1[ks], hf[0][ks], a0, 0,0,0);
            a1 = __builtin_amdgcn_mfma_f32_32x32x16_bf16(cw1[ks], hf[1][ks], a1, 0,0,0);
        }
        int pk[2][4][2];
        #pragma unroll
        for(int q = 0; q < 4; ++q){
            float4 bv = *(const float4*)(b1 + jt*128 + w4*32 + 8*q + 4*hq);
            float bva[4] = {bv.x, bv.y, bv.z, bv.w};
            short4v t0v, t1v;
            #pragma unroll
            for(int r = 0; r < 4; ++r){
                float v0 = a0[4*q+r] + bva[r];
                float v1 = a1[4*q+r] + bva[r];
                t0v[r] = f2bs(v0 > 0.f ? v0 : 0.f);
                t1v[r] = f2bs(v1 > 0.f ? v1 : 0.f);
            }
            int2 u0 = *(int2*)&t0v; int2 u1 = *(int2*)&t1v;
            pk[0][q][0] = u0.x; pk[0][q][1] = u0.y;
            pk[1][q][0] = u1.x; pk[1][q][1] = u1.y;
        }
        #pragma unroll
        for(int g = 0; g < 2; ++g){
            short8 sf[2];
            #pragma unroll
            for(int mt = 0; mt < 2; ++mt){
                int a0i = pk[mt][2*g][0],   a1i = pk[mt][2*g][1];
                int b0i = pk[mt][2*g+1][0], b1i = pk[mt][2*g+1][1];
                int ra0 = __shfl_xor(a0i, 32), ra1 = __shfl_xor(a1i, 32);
                int rb0 = __shfl_xor(b0i, 32), rb1 = __shfl_xor(b1i, 32);
                int4 sfi;
                sfi.x = hq ? rb0 : a0i;
                sfi.y = hq ? rb1 : a1i;
                sfi.z = hq ? b0i : ra0;
                sfi.w = hq ? b1i : ra1;
                sf[mt] = *(short8*)&sfi;
            }
            #pragma unroll
            for(int ct = 0; ct < 3; ++ct){
                acc2[0][ct] = __builtin_amdgcn_mfma_f32_32x32x16_bf16(cw2[g*3+ct], sf[0], acc2[0][ct], 0,0,0);
                acc2[1][ct] = __builtin_amdgcn_mfma_f32_32x32x16_bf16(cw2[g*3+ct], sf[1], acc2[1][ct], 0,0,0);
            }
        }
        #pragma unroll
        for(int ks = 0; ks < 6; ++ks) cw1[ks] = nw1[ks];
        #pragma unroll
        for(int i = 0; i < 6; ++i) cw2[i] = nw2[i];
    }
    __syncthreads();
    #pragma unroll
    for(int mt = 0; mt < 2; ++mt)
        #pragma unroll
        for(int ct = 0; ct < 3; ++ct)
            #pragma unroll
            for(int q = 0; q < 4; ++q)
                #pragma unroll
                for(int r = 0; r < 4; ++r)
                    redp[((w4*2 + mt)*3 + ct)*1088 + lane*17 + 4*q + r] = acc2[mt][ct][4*q+r];
    __syncthreads();
    if(w4 < 2){
        const int mt = w4;
        const int rr = r0 + mt*32;
        float vals[48];
        float p1 = 0.f, p2 = 0.f;
        #pragma unroll
        for(int ct = 0; ct < 3; ++ct){
            #pragma unroll
            for(int q = 0; q < 4; ++q){
                int c = ct*32 + 8*q + 4*hq;
                float4 bv = *(const float4*)(b2 + c);
                short4v hv = *(const short4v*)((const short*)h1b + (size_t)(rr + lm)*96 + c);
                float bva[4] = {bv.x, bv.y, bv.z, bv.w};
                #pragma unroll
                for(int r = 0; r < 4; ++r){
                    float v = redp[((0*2 + mt)*3 + ct)*1088 + lane*17 + 4*q + r]
                            + redp[((1*2 + mt)*3 + ct)*1088 + lane*17 + 4*q + r]
                            + redp[((2*2 + mt)*3 + ct)*1088 + lane*17 + 4*q + r]
                            + redp[((3*2 + mt)*3 + ct)*1088 + lane*17 + 4*q + r]
                            + bva[r] + bs2f(hv[r]);
                    vals[ct*16 + 4*q + r] = v;
                    p1 += v; p2 += v*v;
                }
            }
        }
        p1 += __shfl_xor(p1, 32);
        p2 += __shfl_xor(p2, 32);
        float mu = p1*(1.0f/96.0f);
        float rstd = rsqrtf(p2*(1.0f/96.0f) - mu*mu + 1e-5f);
        float q1 = 0.f, q2 = 0.f;
        #pragma unroll
        for(int ct = 0; ct < 3; ++ct){
            #pragma unroll
            for(int q = 0; q < 4; ++q){
                int c = ct*32 + 8*q + 4*hq;
                float4 gv = *(const float4*)(g2 + c);
                float4 bv = *(const float4*)(bt2 + c);
                float ga[4] = {gv.x, gv.y, gv.z, gv.w};
                float ba[4] = {bv.x, bv.y, bv.z, bv.w};
                #pragma unroll
                for(int r = 0; r < 4; ++r){
                    float y = (vals[ct*16+4*q+r] - mu)*rstd*ga[r] + ba[r];
                    vals[ct*16+4*q+r] = y;
                    q1 += y; q2 += y*y;
                }
            }
        }
        q1 += __shfl_xor(q1, 32);
        q2 += __shfl_xor(q2, 32);
        float mu2 = q1*(1.0f/96.0f);
        float rstd2 = rsqrtf(q2*(1.0f/96.0f) - mu2*mu2 + 1e-5f);
        #pragma unroll
        for(int ct = 0; ct < 3; ++ct){
            #pragma unroll
            for(int q = 0; q < 4; ++q){
                int c = ct*32 + 8*q + 4*hq;
                float4 gv = *(const float4*)(gf + c);
                float4 bv = *(const float4*)(btf + c);
                float ga[4] = {gv.x, gv.y, gv.z, gv.w};
                float ba[4] = {bv.x, bv.y, bv.z, bv.w};
                #pragma unroll
                for(int r = 0; r < 4; ++r)
                    zt[(c + r)*65 + mt*32 + lm] = (vals[ct*16+4*q+r] - mu2)*rstd2*ga[r] + ba[r];
            }
        }
    }
    __syncthreads();
    int bb  = r0 / T;
    int t0g = r0 % T;
    for(int e = tid; e < 96*64; e += 256){
        int c = e >> 6, tt = e & 63;
        out[(size_t)bb*C*T + (size_t)c*T + t0g + tt] = zt[c*65 + tt];
    }
}

extern "C" void kernel_launch(void* const* d_in, const int* in_sizes, int n_in,
                              void* d_out, int out_size, void* d_ws, size_t ws_size,
                              hipStream_t stream) {
    const float* x     = (const float*)d_in[0];
    const float* w_qkv = (const float*)d_in[1];
    const float* b_qkv = (const float*)d_in[2];
    const float* w_out = (const float*)d_in[3];
    const float* b_out = (const float*)d_in[4];
    const float* ln1_g = (const float*)d_in[5];
    const float* ln1_b = (const float*)d_in[6];
    const float* w_ff1 = (const float*)d_in[7];
    const float* b_ff1 = (const float*)d_in[8];
    const float* w_ff2 = (const float*)d_in[9];
    const float* b_ff2 = (const float*)d_in[10];
    const float* ln2_g = (const float*)d_in[11];
    const float* ln2_b = (const float*)d_in[12];
    const float* lnf_g = (const float*)d_in[13];
    const float* lnf_b = (const float*)d_in[14];
    float* out = (float*)d_out;

    // ws map (bytes), total 13.4 MB:
    //   qswz [0, 3.15M)         Q fragment-major [b][h][tile][ks][lane][8]
    //   kswz [3.15M, 6.29M)     K fragment-major
    //   vbuf [6.29M, 9.44M)     V row-major [b][h][t][32]
    //   h1b  [9.44M, 12.58M)    bf16 LN1 output
    //   wts  [12.58M, 13.44M)   bf16 weights (fragment-major)
    char* wsb = (char*)d_ws;
    bf16*  qswz  = (bf16*)wsb;
    bf16*  kswz  = (bf16*)(wsb + 3145728);
    bf16*  vbuf  = (bf16*)(wsb + 6291456);
    bf16*  h1b   = (bf16*)(wsb + 9437184);
    bf16*  wts   = (bf16*)(wsb + 12582912);
    bf16*  wqs   = wts;
    bf16*  wos   = wts + 27648;
    bf16*  w1s   = wts + 36864;
    bf16*  w2s   = wts + 233472;

    cvtw_kernel   <<<1680, 256, 0, stream>>>(w_qkv, w_out, w_ff1, w_ff2, wts);
    qkv_kernel    <<<BT/32, 256, 0, stream>>>(x, wqs, b_qkv, qswz, kswz, vbuf);
    attn_op_kernel<<<B*(T/32), 192, 0, stream>>>(qswz, kswz, vbuf, wos, b_out, x,
                                                 ln1_g, ln1_b, h1b);
    ff_ln_kernel  <<<BT/64, 256, 0, stream>>>(h1b, w1s, b_ff1, w2s, b_ff2,
                                              ln2_g, ln2_b, lnf_g, lnf_b, out);
}